// Round 1
// baseline (2213.446 us; speedup 1.0000x reference)
//
#include <hip/hip_runtime.h>
#include <hip/hip_bf16.h>

#define BATCH 8
#define NANCH 261888
#define KPRE 6000
#define PROP 2000
#define CAP 8192
#define NBUCKET 32768
#define MW 94       // u64 words per row actually used (94*64 = 6016 >= 6000)
#define MSTRIDE 96  // padded stride in u64 words (16B-aligned ulonglong2 loads)
#define IOU_THR 0.7f

typedef unsigned int u32;
typedef unsigned long long u64;

// ---- workspace layout (bytes) ----
#define OFF_HIST 0ull
#define OFF_META (1ull << 20)                               // T[8] ints at +0, cnt[8] ints at +64
#define OFF_CAND (OFF_META + 4096ull)                       // B*CAP*8 = 512 KiB
#define OFF_BOXES (OFF_CAND + (unsigned long long)BATCH * CAP * 8ull)
#define OFF_M ((OFF_BOXES + (unsigned long long)BATCH * KPRE * 16ull + 255ull) & ~255ull)
// total ≈ OFF_M + 8*6000*96*8 + slack ≈ 39.5 MB

__device__ inline u64 shfl64(u64 v, int src) {
  int lo = __shfl((int)(u32)v, src, 64);
  int hi = __shfl((int)(v >> 32), src, 64);
  return ((u64)(u32)hi << 32) | (u32)lo;
}

// ---- 1: histogram of score float-bits ----
__global__ __launch_bounds__(256) void k_hist(const float* __restrict__ probs, u32* __restrict__ hist) {
  int i = blockIdx.x * 256 + threadIdx.x;
  int b = blockIdx.y;
  if (i >= NANCH) return;
  float s = probs[((size_t)b * NANCH + i) * 2 + 1];
  u32 bucket = __float_as_uint(s) >> 15;  // monotone for positive floats; max 0x7F00 < 32768
  atomicAdd(&hist[(size_t)b * NBUCKET + bucket], 1u);
}

// ---- 2: find threshold bucket T (largest T with count(bucket>=T) >= KPRE) ----
__global__ __launch_bounds__(256) void k_thresh(const u32* __restrict__ hist, int* __restrict__ meta) {
  __shared__ u32 csum[256];
  int b = blockIdx.x;
  const u32* h = hist + (size_t)b * NBUCKET;
  u32 s = 0;
  int base = threadIdx.x * 128;
  for (int t = 0; t < 128; ++t) s += h[base + t];
  csum[threadIdx.x] = s;
  __syncthreads();
  if (threadIdx.x == 0) {
    int suffix = 0, T = 0;
    for (int c = 255; c >= 0; --c) {
      int ns = suffix + (int)csum[c];
      if (ns >= KPRE) {
        int run = suffix;
        for (int t = c * 128 + 127; t >= 0; --t) {
          run += (int)h[t];
          if (run >= KPRE) { T = t; break; }
        }
        break;
      }
      suffix = ns;
    }
    meta[b] = T;
  }
}

// ---- 3: compact candidates (bucket >= T) as sortable u64 keys ----
__global__ __launch_bounds__(256) void k_compact(const float* __restrict__ probs, const int* __restrict__ meta,
                                                 int* __restrict__ cnt, u64* __restrict__ cand) {
  int i = blockIdx.x * 256 + threadIdx.x;
  int b = blockIdx.y;
  if (i >= NANCH) return;
  float s = probs[((size_t)b * NANCH + i) * 2 + 1];
  u32 bits = __float_as_uint(s);
  if ((int)(bits >> 15) >= meta[b]) {
    int pos = atomicAdd(&cnt[b], 1);
    if (pos < CAP) cand[(size_t)b * CAP + pos] = ((u64)bits << 32) | (u32)(~(u32)i);
  }
}

// ---- 4: bitonic sort (desc) + gather + box decode ----
__global__ __launch_bounds__(1024) void k_sortbox(const u64* __restrict__ cand, const int* __restrict__ cnt,
                                                  const float* __restrict__ anchors, const float* __restrict__ bbox,
                                                  float4* __restrict__ boxes) {
  __shared__ u64 sk[CAP];  // 64 KiB
  int b = blockIdx.x;
  int C = cnt[b]; if (C > CAP) C = CAP;
  for (int r = threadIdx.x; r < CAP; r += 1024)
    sk[r] = (r < (int)C) ? cand[(size_t)b * CAP + r] : 0ull;
  __syncthreads();
  for (int ksz = 2; ksz <= CAP; ksz <<= 1) {
    for (int j = ksz >> 1; j > 0; j >>= 1) {
      #pragma unroll
      for (int p = 0; p < CAP / 1024; ++p) {
        int i = threadIdx.x + p * 1024;
        int ixj = i ^ j;
        if (ixj > i) {
          u64 a = sk[i], c2 = sk[ixj];
          bool up = (i & ksz) == 0;
          if ((a < c2) == up) { sk[i] = c2; sk[ixj] = a; }  // descending overall
        }
      }
      __syncthreads();
    }
  }
  for (int r = threadIdx.x; r < KPRE; r += 1024) {
    u64 key = sk[r];
    u32 idx = ~(u32)key;
    const float4 a  = ((const float4*)anchors)[(size_t)b * NANCH + idx];
    const float4 dr = ((const float4*)bbox)[(size_t)b * NANCH + idx];
    float d0 = __fmul_rn(dr.x, 0.1f), d1 = __fmul_rn(dr.y, 0.1f);
    float d2 = __fmul_rn(dr.z, 0.2f), d3 = __fmul_rn(dr.w, 0.2f);
    float h = __fsub_rn(a.z, a.x);
    float w = __fsub_rn(a.w, a.y);
    float cy = __fadd_rn(a.x, __fmul_rn(0.5f, h));
    float cx = __fadd_rn(a.y, __fmul_rn(0.5f, w));
    cy = __fadd_rn(cy, __fmul_rn(d0, h));
    cx = __fadd_rn(cx, __fmul_rn(d1, w));
    h = __fmul_rn(h, (float)exp((double)d2));
    w = __fmul_rn(w, (float)exp((double)d3));
    float y1 = __fsub_rn(cy, __fmul_rn(0.5f, h));
    float x1 = __fsub_rn(cx, __fmul_rn(0.5f, w));
    float4 o; o.x = y1; o.y = x1; o.z = __fadd_rn(y1, h); o.w = __fadd_rn(x1, w);
    boxes[(size_t)b * KPRE + r] = o;
  }
}

// ---- 5: suppression bitmask matrix M[b][r][w] : bit k = (IoU(r, w*64+k) > thr) && (c > r) ----
__global__ __launch_bounds__(256) void k_mask(const float4* __restrict__ boxes, u64* __restrict__ M) {
  __shared__ float4 sb[KPRE];  // 96000 B
  __shared__ float  sa[KPRE];  // 24000 B
  int b = blockIdx.y;
  const float4* bb = boxes + (size_t)b * KPRE;
  for (int t = threadIdx.x; t < KPRE; t += 256) {
    float4 v = bb[t];
    sb[t] = v;
    sa[t] = __fmul_rn(__fsub_rn(v.z, v.x), __fsub_rn(v.w, v.y));
  }
  __syncthreads();
  int r0 = blockIdx.x * 64;
  u64* Mb = M + (size_t)b * KPRE * MSTRIDE;
  for (int task = threadIdx.x; task < 64 * MW; task += 256) {
    int rl = task / MW;
    int w = task - rl * MW;
    int r = r0 + rl;
    if (r >= KPRE) continue;
    int cbase = w << 6;
    u64 bits = 0;
    if (cbase + 63 > r) {
      float4 br = sb[r];
      float ar = sa[r];
      int kmax = KPRE - cbase; if (kmax > 64) kmax = 64;
      for (int k2 = 0; k2 < kmax; ++k2) {
        int c = cbase + k2;
        float4 bc = sb[c];
        float iy1 = fmaxf(br.x, bc.x);
        float ix1 = fmaxf(br.y, bc.y);
        float iy2 = fminf(br.z, bc.z);
        float ix2 = fminf(br.w, bc.w);
        float ih = fmaxf(__fsub_rn(iy2, iy1), 0.0f);
        float iw = fmaxf(__fsub_rn(ix2, ix1), 0.0f);
        float inter = __fmul_rn(ih, iw);
        float uni = __fsub_rn(__fadd_rn(ar, sa[c]), inter);
        float q = __fdiv_rn(inter, fmaxf(uni, 1e-12f));
        if ((q > IOU_THR) && (c > r)) bits |= (1ull << k2);
      }
    }
    Mb[(size_t)r * MSTRIDE + w] = bits;
  }
}

// ---- 6: sequential greedy NMS scan — one wave per batch, keep mask in registers ----
__global__ __launch_bounds__(64) void k_scan(const u64* __restrict__ M, const float4* __restrict__ boxes,
                                             float4* __restrict__ out) {
  int b = blockIdx.x;
  int lane = threadIdx.x;
  const u64* Mb = M + (size_t)b * KPRE * MSTRIDE;
  const float4* bb = boxes + (size_t)b * KPRE;
  float4* ob = out + (size_t)b * PROP;
  u64 kw0 = ~0ull, kw1 = ~0ull;  // lane owns keep-words 2*lane, 2*lane+1
  int count = 0;
  for (int w = 0; w < MW && count < PROP; ++w) {
    int src = w >> 1;
    u64 cur = shfl64((w & 1) ? kw1 : kw0, src);  // replicated current keep-word
    int kmax = KPRE - (w << 6); if (kmax > 64) kmax = 64;
    for (int k2 = 0; k2 < kmax; ++k2) {
      int i = (w << 6) + k2;
      const u64* row = Mb + (size_t)i * MSTRIDE;
      ulonglong2 mm = ((const ulonglong2*)row)[lane];  // lanes>=48 read past row: harmless (unused bits)
      u64 ms = row[w];                                 // broadcast word
      bool kept = (cur >> k2) & 1ull;
      u64 sel = kept ? ~0ull : 0ull;
      cur &= ~(ms & sel);
      kw0 &= ~(mm.x & sel);
      kw1 &= ~(mm.y & sel);
      if (kept) {
        if (lane == 0) ob[count] = bb[i];
        ++count;
        if (count >= PROP) break;
      }
    }
  }
}

extern "C" void kernel_launch(void* const* d_in, const int* in_sizes, int n_in,
                              void* d_out, int out_size, void* d_ws, size_t ws_size,
                              hipStream_t stream) {
  const float* probs   = (const float*)d_in[0];
  const float* bbox    = (const float*)d_in[1];
  const float* anchors = (const float*)d_in[2];
  char* ws = (char*)d_ws;
  u32* hist   = (u32*)(ws + OFF_HIST);
  int* meta   = (int*)(ws + OFF_META);        // T[8]
  int* cnt    = (int*)(ws + OFF_META + 64);   // cnt[8]
  u64* cand   = (u64*)(ws + OFF_CAND);
  float4* boxes = (float4*)(ws + OFF_BOXES);
  u64* M      = (u64*)(ws + OFF_M);
  float4* out = (float4*)d_out;

  hipMemsetAsync(hist, 0, (size_t)BATCH * NBUCKET * 4, stream);
  hipMemsetAsync(cnt, 0, 64, stream);
  hipMemsetAsync(d_out, 0, (size_t)out_size * 4, stream);

  dim3 g1((NANCH + 255) / 256, BATCH);
  k_hist<<<g1, 256, 0, stream>>>(probs, hist);
  k_thresh<<<BATCH, 256, 0, stream>>>(hist, meta);
  k_compact<<<g1, 256, 0, stream>>>(probs, meta, cnt, cand);
  k_sortbox<<<BATCH, 1024, 0, stream>>>(cand, cnt, anchors, bbox, boxes);
  dim3 gm((KPRE + 63) / 64, BATCH);
  k_mask<<<gm, 256, 0, stream>>>(boxes, M);
  k_scan<<<BATCH, 64, 0, stream>>>(M, boxes, out);
}

// Round 2
// 1424.722 us; speedup vs baseline: 1.5536x; 1.5536x over previous
//
#include <hip/hip_runtime.h>
#include <hip/hip_bf16.h>

#define BATCH 8
#define NANCH 261888
#define KPRE 6000
#define PROP 2000
#define CAP 8192
#define NBUCKET 32768
#define MW 94       // u64 words per row actually used (94*64 = 6016 >= 6000)
#define MSTRIDE 96  // padded stride in u64 words (16B-aligned ulonglong2 loads)
#define IOU_THR 0.7f

typedef unsigned int u32;
typedef unsigned long long u64;

// ---- workspace layout (bytes) ----
#define OFF_HIST 0ull
#define OFF_META (1ull << 20)                               // T[8] ints at +0, cnt[8] ints at +64
#define OFF_CAND (OFF_META + 4096ull)                       // B*CAP*8 = 512 KiB
#define OFF_BOXES (OFF_CAND + (unsigned long long)BATCH * CAP * 8ull)
#define OFF_M ((OFF_BOXES + (unsigned long long)BATCH * KPRE * 16ull + 255ull) & ~255ull)
// total ≈ OFF_M + 8*6000*96*8 + slack ≈ 39.5 MB

__device__ inline u64 shfl64(u64 v, int src) {
  int lo = __shfl((int)(u32)v, src, 64);
  int hi = __shfl((int)(v >> 32), src, 64);
  return ((u64)(u32)hi << 32) | (u32)lo;
}

// ---- 1: histogram of score float-bits ----
__global__ __launch_bounds__(256) void k_hist(const float* __restrict__ probs, u32* __restrict__ hist) {
  int i = blockIdx.x * 256 + threadIdx.x;
  int b = blockIdx.y;
  if (i >= NANCH) return;
  float s = probs[((size_t)b * NANCH + i) * 2 + 1];
  u32 bucket = __float_as_uint(s) >> 15;  // monotone for positive floats; max 0x7F00 < 32768
  atomicAdd(&hist[(size_t)b * NBUCKET + bucket], 1u);
}

// ---- 2: find threshold bucket T (largest T with count(bucket>=T) >= KPRE) ----
__global__ __launch_bounds__(256) void k_thresh(const u32* __restrict__ hist, int* __restrict__ meta) {
  __shared__ u32 csum[256];
  int b = blockIdx.x;
  const u32* h = hist + (size_t)b * NBUCKET;
  u32 s = 0;
  int base = threadIdx.x * 128;
  for (int t = 0; t < 128; ++t) s += h[base + t];
  csum[threadIdx.x] = s;
  __syncthreads();
  if (threadIdx.x == 0) {
    int suffix = 0, T = 0;
    for (int c = 255; c >= 0; --c) {
      int ns = suffix + (int)csum[c];
      if (ns >= KPRE) {
        int run = suffix;
        for (int t = c * 128 + 127; t >= 0; --t) {
          run += (int)h[t];
          if (run >= KPRE) { T = t; break; }
        }
        break;
      }
      suffix = ns;
    }
    meta[b] = T;
  }
}

// ---- 3: compact candidates (bucket >= T) as sortable u64 keys ----
__global__ __launch_bounds__(256) void k_compact(const float* __restrict__ probs, const int* __restrict__ meta,
                                                 int* __restrict__ cnt, u64* __restrict__ cand) {
  int i = blockIdx.x * 256 + threadIdx.x;
  int b = blockIdx.y;
  if (i >= NANCH) return;
  float s = probs[((size_t)b * NANCH + i) * 2 + 1];
  u32 bits = __float_as_uint(s);
  if ((int)(bits >> 15) >= meta[b]) {
    int pos = atomicAdd(&cnt[b], 1);
    if (pos < CAP) cand[(size_t)b * CAP + pos] = ((u64)bits << 32) | (u32)(~(u32)i);
  }
}

// ---- 4: bitonic sort (desc) + gather + box decode ----
__global__ __launch_bounds__(1024) void k_sortbox(const u64* __restrict__ cand, const int* __restrict__ cnt,
                                                  const float* __restrict__ anchors, const float* __restrict__ bbox,
                                                  float4* __restrict__ boxes) {
  __shared__ u64 sk[CAP];  // 64 KiB
  int b = blockIdx.x;
  int C = cnt[b]; if (C > CAP) C = CAP;
  for (int r = threadIdx.x; r < CAP; r += 1024)
    sk[r] = (r < (int)C) ? cand[(size_t)b * CAP + r] : 0ull;
  __syncthreads();
  for (int ksz = 2; ksz <= CAP; ksz <<= 1) {
    for (int j = ksz >> 1; j > 0; j >>= 1) {
      #pragma unroll
      for (int p = 0; p < CAP / 1024; ++p) {
        int i = threadIdx.x + p * 1024;
        int ixj = i ^ j;
        if (ixj > i) {
          u64 a = sk[i], c2 = sk[ixj];
          bool up = (i & ksz) == 0;
          if ((a < c2) == up) { sk[i] = c2; sk[ixj] = a; }  // descending overall
        }
      }
      __syncthreads();
    }
  }
  for (int r = threadIdx.x; r < KPRE; r += 1024) {
    u64 key = sk[r];
    u32 idx = ~(u32)key;
    const float4 a  = ((const float4*)anchors)[(size_t)b * NANCH + idx];
    const float4 dr = ((const float4*)bbox)[(size_t)b * NANCH + idx];
    float d0 = __fmul_rn(dr.x, 0.1f), d1 = __fmul_rn(dr.y, 0.1f);
    float d2 = __fmul_rn(dr.z, 0.2f), d3 = __fmul_rn(dr.w, 0.2f);
    float h = __fsub_rn(a.z, a.x);
    float w = __fsub_rn(a.w, a.y);
    float cy = __fadd_rn(a.x, __fmul_rn(0.5f, h));
    float cx = __fadd_rn(a.y, __fmul_rn(0.5f, w));
    cy = __fadd_rn(cy, __fmul_rn(d0, h));
    cx = __fadd_rn(cx, __fmul_rn(d1, w));
    h = __fmul_rn(h, (float)exp((double)d2));
    w = __fmul_rn(w, (float)exp((double)d3));
    float y1 = __fsub_rn(cy, __fmul_rn(0.5f, h));
    float x1 = __fsub_rn(cx, __fmul_rn(0.5f, w));
    float4 o; o.x = y1; o.y = x1; o.z = __fadd_rn(y1, h); o.w = __fadd_rn(x1, w);
    boxes[(size_t)b * KPRE + r] = o;
  }
}

// ---- 5: suppression bitmask matrix M[b][r][w] : bit k = (IoU(r, w*64+k) > thr) && (c > r) ----
__global__ __launch_bounds__(256) void k_mask(const float4* __restrict__ boxes, u64* __restrict__ M) {
  __shared__ float4 sb[KPRE];  // 96000 B
  __shared__ float  sa[KPRE];  // 24000 B
  int b = blockIdx.y;
  const float4* bb = boxes + (size_t)b * KPRE;
  for (int t = threadIdx.x; t < KPRE; t += 256) {
    float4 v = bb[t];
    sb[t] = v;
    sa[t] = __fmul_rn(__fsub_rn(v.z, v.x), __fsub_rn(v.w, v.y));
  }
  __syncthreads();
  int r0 = blockIdx.x * 64;
  u64* Mb = M + (size_t)b * KPRE * MSTRIDE;
  for (int task = threadIdx.x; task < 64 * MW; task += 256) {
    int rl = task / MW;
    int w = task - rl * MW;
    int r = r0 + rl;
    if (r >= KPRE) continue;
    int cbase = w << 6;
    u64 bits = 0;
    if (cbase + 63 > r) {
      float4 br = sb[r];
      float ar = sa[r];
      int kmax = KPRE - cbase; if (kmax > 64) kmax = 64;
      for (int k2 = 0; k2 < kmax; ++k2) {
        int c = cbase + k2;
        float4 bc = sb[c];
        float iy1 = fmaxf(br.x, bc.x);
        float ix1 = fmaxf(br.y, bc.y);
        float iy2 = fminf(br.z, bc.z);
        float ix2 = fminf(br.w, bc.w);
        float ih = fmaxf(__fsub_rn(iy2, iy1), 0.0f);
        float iw = fmaxf(__fsub_rn(ix2, ix1), 0.0f);
        float inter = __fmul_rn(ih, iw);
        float uni = __fsub_rn(__fadd_rn(ar, sa[c]), inter);
        float q = __fdiv_rn(inter, fmaxf(uni, 1e-12f));
        if ((q > IOU_THR) && (c > r)) bits |= (1ull << k2);
      }
    }
    Mb[(size_t)r * MSTRIDE + w] = bits;
  }
}

// ---- 6: block-parallel greedy NMS scan — one block (4 waves) per batch ----
// Lane l of each wave owns keep-words 2l, 2l+1 (words >= MW unused; lanes >= 47 idle for bulk loads).
__global__ __launch_bounds__(256) void k_scan(const u64* __restrict__ M, const float4* __restrict__ boxes,
                                              float4* __restrict__ out) {
  __shared__ u64 xch[2][4];
  __shared__ u64 fin[MW];
  __shared__ int pfx[MW];
  int b = blockIdx.x;
  int tid = threadIdx.x;
  int lane = tid & 63;
  int wv = tid >> 6;
  const u64* Mb = M + (size_t)b * KPRE * MSTRIDE;

  if (tid < MW) fin[tid] = 0ull;

  u64 kw0 = ~0ull, kw1 = ~0ull;
  u64 cur = ~0ull;
  // prefetch diag words for block 0 (rows 0..63, word 0)
  u64 dw = Mb[(size_t)lane * MSTRIDE + 0];
  int count = 0;

  for (int w = 0; w < MW; ++w) {
    int rem = KPRE - (w << 6);
    u64 valid = (rem >= 64) ? ~0ull : ((1ull << rem) - 1ull);
    cur &= valid;

    // --- intra-block resolve (register-only, sparse) ---
    u64 nz = __ballot(dw != 0ull);
    u64 pend = cur & nz;
    while (pend) {
      int k = (int)__builtin_ctzll(pend);
      u64 d = shfl64(dw, k);   // bit k of d is 0 (c>r strict), so row k stays kept
      cur &= ~d;
      pend &= (pend - 1);
      pend &= cur;             // drop pending rows that just got suppressed
    }

    if (tid == 0) fin[w] = cur;
    count += (int)__popcll(cur);
    if (count >= PROP || w == MW - 1) break;

    // --- prefetch next block's diag words ---
    {
      int r = ((w + 1) << 6) + lane;
      dw = (r < KPRE) ? Mb[(size_t)r * MSTRIDE + (w + 1)] : 0ull;
    }

    // --- bulk apply: 4 waves split the 64 rows; 16 independent loads/lane ---
    bool lactive = (lane < 47) && (2 * lane + 1 >= w + 1);
    ulonglong2 mm[16];
    #pragma unroll
    for (int kk = 0; kk < 16; ++kk) {
      int r = (w << 6) + wv + (kk << 2);
      ulonglong2 t2; t2.x = 0ull; t2.y = 0ull;
      if (lactive && r < KPRE)
        t2 = ((const ulonglong2*)(Mb + (size_t)r * MSTRIDE))[lane];
      mm[kk] = t2;
    }
    #pragma unroll
    for (int kk = 0; kk < 16; ++kk) {
      int k = wv + (kk << 2);
      u64 sel = 0ull - ((cur >> k) & 1ull);
      kw0 &= ~(mm[kk].x & sel);
      kw1 &= ~(mm[kk].y & sel);
    }

    // --- exchange: AND the 4 waves' copies of word w+1 (parity double-buffer) ---
    int nw = w + 1;
    if (lane == (nw >> 1)) xch[nw & 1][wv] = (nw & 1) ? kw1 : kw0;
    __syncthreads();
    cur = xch[nw & 1][0] & xch[nw & 1][1] & xch[nw & 1][2] & xch[nw & 1][3];
  }
  __syncthreads();

  if (tid == 0) {
    int s = 0;
    for (int t = 0; t < MW; ++t) { pfx[t] = s; s += (int)__popcll(fin[t]); }
  }
  __syncthreads();

  const float4* bb = boxes + (size_t)b * KPRE;
  float4* ob = out + (size_t)b * PROP;
  if (tid < MW) {
    u64 bits = fin[tid];
    int slot = pfx[tid];
    while (bits && slot < PROP) {
      int k = (int)__builtin_ctzll(bits);
      ob[slot] = bb[(tid << 6) + k];
      ++slot;
      bits &= bits - 1;
    }
  }
}

extern "C" void kernel_launch(void* const* d_in, const int* in_sizes, int n_in,
                              void* d_out, int out_size, void* d_ws, size_t ws_size,
                              hipStream_t stream) {
  const float* probs   = (const float*)d_in[0];
  const float* bbox    = (const float*)d_in[1];
  const float* anchors = (const float*)d_in[2];
  char* ws = (char*)d_ws;
  u32* hist   = (u32*)(ws + OFF_HIST);
  int* meta   = (int*)(ws + OFF_META);        // T[8]
  int* cnt    = (int*)(ws + OFF_META + 64);   // cnt[8]
  u64* cand   = (u64*)(ws + OFF_CAND);
  float4* boxes = (float4*)(ws + OFF_BOXES);
  u64* M      = (u64*)(ws + OFF_M);
  float4* out = (float4*)d_out;

  hipMemsetAsync(hist, 0, (size_t)BATCH * NBUCKET * 4, stream);
  hipMemsetAsync(cnt, 0, 64, stream);
  hipMemsetAsync(d_out, 0, (size_t)out_size * 4, stream);

  dim3 g1((NANCH + 255) / 256, BATCH);
  k_hist<<<g1, 256, 0, stream>>>(probs, hist);
  k_thresh<<<BATCH, 256, 0, stream>>>(hist, meta);
  k_compact<<<g1, 256, 0, stream>>>(probs, meta, cnt, cand);
  k_sortbox<<<BATCH, 1024, 0, stream>>>(cand, cnt, anchors, bbox, boxes);
  dim3 gm((KPRE + 63) / 64, BATCH);
  k_mask<<<gm, 256, 0, stream>>>(boxes, M);
  k_scan<<<BATCH, 256, 0, stream>>>(M, boxes, out);
}

// Round 3
// 1020.389 us; speedup vs baseline: 2.1692x; 1.3963x over previous
//
#include <hip/hip_runtime.h>
#include <hip/hip_bf16.h>

#define BATCH 8
#define NANCH 261888
#define KPRE 6000
#define PROP 2000
#define CAP 8192
#define NBUCKET 32768
#define MW 94       // u64 words per row actually used (94*64 = 6016 >= 6000)
#define MSTRIDE 96  // padded stride in u64 words (16B-aligned ulonglong2 loads)
#define IOU_THR 0.7f
#define WB 24       // mask col-chunk size in words (4 chunks: 24,24,24,22)

typedef unsigned int u32;
typedef unsigned long long u64;

// ---- workspace layout (bytes) ----
#define OFF_HIST 0ull
#define OFF_META (1ull << 20)                               // T[8] ints at +0, cnt[8] ints at +64
#define OFF_CAND (OFF_META + 4096ull)                       // B*CAP*8 = 512 KiB
#define OFF_BOXES (OFF_CAND + (unsigned long long)BATCH * CAP * 8ull)
#define OFF_M ((OFF_BOXES + (unsigned long long)BATCH * KPRE * 16ull + 255ull) & ~255ull)
// total ≈ OFF_M + 8*6000*96*8 + slack ≈ 39.5 MB

__device__ inline u64 shfl64(u64 v, int src) {
  int lo = __shfl((int)(u32)v, src, 64);
  int hi = __shfl((int)(v >> 32), src, 64);
  return ((u64)(u32)hi << 32) | (u32)lo;
}

// ---- 1: histogram of score float-bits ----
__global__ __launch_bounds__(256) void k_hist(const float* __restrict__ probs, u32* __restrict__ hist) {
  int i = blockIdx.x * 256 + threadIdx.x;
  int b = blockIdx.y;
  if (i >= NANCH) return;
  float s = probs[((size_t)b * NANCH + i) * 2 + 1];
  u32 bucket = __float_as_uint(s) >> 15;  // monotone for positive floats; max 0x7F00 < 32768
  atomicAdd(&hist[(size_t)b * NBUCKET + bucket], 1u);
}

// ---- 2: find threshold bucket T (largest T with count(bucket>=T) >= KPRE) ----
__global__ __launch_bounds__(256) void k_thresh(const u32* __restrict__ hist, int* __restrict__ meta) {
  __shared__ u32 csum[256];
  int b = blockIdx.x;
  const u32* h = hist + (size_t)b * NBUCKET;
  u32 s = 0;
  int base = threadIdx.x * 128;
  for (int t = 0; t < 128; ++t) s += h[base + t];
  csum[threadIdx.x] = s;
  __syncthreads();
  if (threadIdx.x == 0) {
    int suffix = 0, T = 0;
    for (int c = 255; c >= 0; --c) {
      int ns = suffix + (int)csum[c];
      if (ns >= KPRE) {
        int run = suffix;
        for (int t = c * 128 + 127; t >= 0; --t) {
          run += (int)h[t];
          if (run >= KPRE) { T = t; break; }
        }
        break;
      }
      suffix = ns;
    }
    meta[b] = T;
  }
}

// ---- 3: compact candidates (bucket >= T) as sortable u64 keys ----
__global__ __launch_bounds__(256) void k_compact(const float* __restrict__ probs, const int* __restrict__ meta,
                                                 int* __restrict__ cnt, u64* __restrict__ cand) {
  int i = blockIdx.x * 256 + threadIdx.x;
  int b = blockIdx.y;
  if (i >= NANCH) return;
  float s = probs[((size_t)b * NANCH + i) * 2 + 1];
  u32 bits = __float_as_uint(s);
  if ((int)(bits >> 15) >= meta[b]) {
    int pos = atomicAdd(&cnt[b], 1);
    if (pos < CAP) cand[(size_t)b * CAP + pos] = ((u64)bits << 32) | (u32)(~(u32)i);
  }
}

// ---- 4: bitonic sort (desc) + gather + box decode ----
__global__ __launch_bounds__(1024) void k_sortbox(const u64* __restrict__ cand, const int* __restrict__ cnt,
                                                  const float* __restrict__ anchors, const float* __restrict__ bbox,
                                                  float4* __restrict__ boxes) {
  __shared__ u64 sk[CAP];  // 64 KiB
  int b = blockIdx.x;
  int C = cnt[b]; if (C > CAP) C = CAP;
  for (int r = threadIdx.x; r < CAP; r += 1024)
    sk[r] = (r < (int)C) ? cand[(size_t)b * CAP + r] : 0ull;
  __syncthreads();
  for (int ksz = 2; ksz <= CAP; ksz <<= 1) {
    for (int j = ksz >> 1; j > 0; j >>= 1) {
      #pragma unroll
      for (int p = 0; p < CAP / 1024; ++p) {
        int i = threadIdx.x + p * 1024;
        int ixj = i ^ j;
        if (ixj > i) {
          u64 a = sk[i], c2 = sk[ixj];
          bool up = (i & ksz) == 0;
          if ((a < c2) == up) { sk[i] = c2; sk[ixj] = a; }  // descending overall
        }
      }
      __syncthreads();
    }
  }
  for (int r = threadIdx.x; r < KPRE; r += 1024) {
    u64 key = sk[r];
    u32 idx = ~(u32)key;
    const float4 a  = ((const float4*)anchors)[(size_t)b * NANCH + idx];
    const float4 dr = ((const float4*)bbox)[(size_t)b * NANCH + idx];
    float d0 = __fmul_rn(dr.x, 0.1f), d1 = __fmul_rn(dr.y, 0.1f);
    float d2 = __fmul_rn(dr.z, 0.2f), d3 = __fmul_rn(dr.w, 0.2f);
    float h = __fsub_rn(a.z, a.x);
    float w = __fsub_rn(a.w, a.y);
    float cy = __fadd_rn(a.x, __fmul_rn(0.5f, h));
    float cx = __fadd_rn(a.y, __fmul_rn(0.5f, w));
    cy = __fadd_rn(cy, __fmul_rn(d0, h));
    cx = __fadd_rn(cx, __fmul_rn(d1, w));
    h = __fmul_rn(h, (float)exp((double)d2));
    w = __fmul_rn(w, (float)exp((double)d3));
    float y1 = __fsub_rn(cy, __fmul_rn(0.5f, h));
    float x1 = __fsub_rn(cx, __fmul_rn(0.5f, w));
    float4 o; o.x = y1; o.y = x1; o.z = __fadd_rn(y1, h); o.w = __fadd_rn(x1, w);
    boxes[(size_t)b * KPRE + r] = o;
  }
}

// ---- 5: suppression bitmask M[b][r][w], bit k = (IoU(r, c=w*64+k) > thr) && (c > r) ----
// Thread owns ROW (box in regs); wave walks columns together -> LDS same-address broadcast,
// zero bank conflicts. Columns staged per chunk (30 KiB) -> ~5 blocks/CU.
__global__ __launch_bounds__(256) void k_mask(const float4* __restrict__ boxes, u64* __restrict__ M) {
  __shared__ float4 sb[WB * 64];
  __shared__ float  sa[WB * 64];
  int b = blockIdx.z;
  int rowblk = blockIdx.x;   // 0..23 (256 rows each)
  int chunk = blockIdx.y;    // 0..3
  int w0 = chunk * WB;
  int w1 = w0 + WB; if (w1 > MW) w1 = MW;
  int c0 = w0 << 6;
  int ncol = (w1 - w0) << 6;
  const float4* bb = boxes + (size_t)b * KPRE;

  for (int t = threadIdx.x; t < ncol; t += 256) {
    int c = c0 + t;
    float4 v;
    if (c < KPRE) v = bb[c];
    else { v.x = 0.f; v.y = 0.f; v.z = 0.f; v.w = 0.f; }  // pad: area 0 -> iou 0 -> no bit
    sb[t] = v;
    sa[t] = __fmul_rn(__fsub_rn(v.z, v.x), __fsub_rn(v.w, v.y));
  }
  __syncthreads();

  int r = rowblk * 256 + threadIdx.x;
  bool rvalid = r < KPRE;
  float4 br;
  if (rvalid) br = bb[r];
  else { br.x = 0.f; br.y = 0.f; br.z = 0.f; br.w = 0.f; }
  float ar = __fmul_rn(__fsub_rn(br.z, br.x), __fsub_rn(br.w, br.y));
  u64* Mr = M + ((size_t)b * KPRE + (size_t)(rvalid ? r : 0)) * MSTRIDE;

  for (int w = w0; w < w1; ++w) {
    int cbase = w << 6;
    u64 bits = 0;
    if (rvalid && (cbase + 63 > r)) {       // upper-triangle only (wave-granular skip)
      int tb = (w - w0) << 6;
      #pragma unroll 4
      for (int k2 = 0; k2 < 64; ++k2) {
        float4 bc = sb[tb + k2];            // wave-uniform address: LDS broadcast
        float ac = sa[tb + k2];
        float iy1 = fmaxf(br.x, bc.x);
        float ix1 = fmaxf(br.y, bc.y);
        float iy2 = fminf(br.z, bc.z);
        float ix2 = fminf(br.w, bc.w);
        float ih = fmaxf(__fsub_rn(iy2, iy1), 0.0f);
        float iw = fmaxf(__fsub_rn(ix2, ix1), 0.0f);
        float inter = __fmul_rn(ih, iw);
        float uni = __fsub_rn(__fadd_rn(ar, ac), inter);
        float q = __fdiv_rn(inter, fmaxf(uni, 1e-12f));
        if (q > IOU_THR) bits |= (1ull << k2);
      }
      // keep only c > r within the straddling word
      if (cbase <= r) bits &= ~((r - cbase >= 63) ? ~0ull : ((1ull << (r - cbase + 1)) - 1ull));
    }
    if (rvalid) Mr[w] = bits;
  }
}

// ---- 6: block-parallel greedy NMS scan — one block (4 waves) per batch ----
__global__ __launch_bounds__(256) void k_scan(const u64* __restrict__ M, const float4* __restrict__ boxes,
                                              float4* __restrict__ out) {
  __shared__ u64 xch[2][4];
  __shared__ u64 fin[MW];
  __shared__ int pfx[MW];
  int b = blockIdx.x;
  int tid = threadIdx.x;
  int lane = tid & 63;
  int wv = tid >> 6;
  const u64* Mb = M + (size_t)b * KPRE * MSTRIDE;

  if (tid < MW) fin[tid] = 0ull;

  u64 kw0 = ~0ull, kw1 = ~0ull;
  u64 cur = ~0ull;
  u64 dw = Mb[(size_t)lane * MSTRIDE + 0];
  int count = 0;

  for (int w = 0; w < MW; ++w) {
    int rem = KPRE - (w << 6);
    u64 valid = (rem >= 64) ? ~0ull : ((1ull << rem) - 1ull);
    cur &= valid;

    u64 nz = __ballot(dw != 0ull);
    u64 pend = cur & nz;
    while (pend) {
      int k = (int)__builtin_ctzll(pend);
      u64 d = shfl64(dw, k);
      cur &= ~d;
      pend &= (pend - 1);
      pend &= cur;
    }

    if (tid == 0) fin[w] = cur;
    count += (int)__popcll(cur);
    if (count >= PROP || w == MW - 1) break;

    {
      int r = ((w + 1) << 6) + lane;
      dw = (r < KPRE) ? Mb[(size_t)r * MSTRIDE + (w + 1)] : 0ull;
    }

    bool lactive = (lane < 47) && (2 * lane + 1 >= w + 1);
    ulonglong2 mm[16];
    #pragma unroll
    for (int kk = 0; kk < 16; ++kk) {
      int r = (w << 6) + wv + (kk << 2);
      ulonglong2 t2; t2.x = 0ull; t2.y = 0ull;
      if (lactive && r < KPRE)
        t2 = ((const ulonglong2*)(Mb + (size_t)r * MSTRIDE))[lane];
      mm[kk] = t2;
    }
    #pragma unroll
    for (int kk = 0; kk < 16; ++kk) {
      int k = wv + (kk << 2);
      u64 sel = 0ull - ((cur >> k) & 1ull);
      kw0 &= ~(mm[kk].x & sel);
      kw1 &= ~(mm[kk].y & sel);
    }

    int nw = w + 1;
    if (lane == (nw >> 1)) xch[nw & 1][wv] = (nw & 1) ? kw1 : kw0;
    __syncthreads();
    cur = xch[nw & 1][0] & xch[nw & 1][1] & xch[nw & 1][2] & xch[nw & 1][3];
  }
  __syncthreads();

  if (tid == 0) {
    int s = 0;
    for (int t = 0; t < MW; ++t) { pfx[t] = s; s += (int)__popcll(fin[t]); }
  }
  __syncthreads();

  const float4* bb = boxes + (size_t)b * KPRE;
  float4* ob = out + (size_t)b * PROP;
  if (tid < MW) {
    u64 bits = fin[tid];
    int slot = pfx[tid];
    while (bits && slot < PROP) {
      int k = (int)__builtin_ctzll(bits);
      ob[slot] = bb[(tid << 6) + k];
      ++slot;
      bits &= bits - 1;
    }
  }
}

extern "C" void kernel_launch(void* const* d_in, const int* in_sizes, int n_in,
                              void* d_out, int out_size, void* d_ws, size_t ws_size,
                              hipStream_t stream) {
  const float* probs   = (const float*)d_in[0];
  const float* bbox    = (const float*)d_in[1];
  const float* anchors = (const float*)d_in[2];
  char* ws = (char*)d_ws;
  u32* hist   = (u32*)(ws + OFF_HIST);
  int* meta   = (int*)(ws + OFF_META);        // T[8]
  int* cnt    = (int*)(ws + OFF_META + 64);   // cnt[8]
  u64* cand   = (u64*)(ws + OFF_CAND);
  float4* boxes = (float4*)(ws + OFF_BOXES);
  u64* M      = (u64*)(ws + OFF_M);
  float4* out = (float4*)d_out;

  hipMemsetAsync(hist, 0, (size_t)BATCH * NBUCKET * 4, stream);
  hipMemsetAsync(cnt, 0, 64, stream);
  hipMemsetAsync(d_out, 0, (size_t)out_size * 4, stream);

  dim3 g1((NANCH + 255) / 256, BATCH);
  k_hist<<<g1, 256, 0, stream>>>(probs, hist);
  k_thresh<<<BATCH, 256, 0, stream>>>(hist, meta);
  k_compact<<<g1, 256, 0, stream>>>(probs, meta, cnt, cand);
  k_sortbox<<<BATCH, 1024, 0, stream>>>(cand, cnt, anchors, bbox, boxes);
  dim3 gm(24, 4, BATCH);
  k_mask<<<gm, 256, 0, stream>>>(boxes, M);
  k_scan<<<BATCH, 256, 0, stream>>>(M, boxes, out);
}

// Round 5
// 483.839 us; speedup vs baseline: 4.5748x; 2.1089x over previous
//
#include <hip/hip_runtime.h>
#include <hip/hip_bf16.h>

#define BATCH 8
#define NANCH 261888
#define KPRE 6000
#define PROP 2000
#define CAP 8192
#define NBUCKET 32768
#define MW 94       // u64 words per row actually used (94*64 = 6016 >= 6000)
#define MSTRIDE 96  // padded stride in u64 words (16B-aligned ulonglong2 loads)
#define IOU_THR 0.7f
#define WB 24       // mask col-chunk size in words (4 chunks: 24,24,24,22)
#define HB 16       // histogram blocks per batch

typedef unsigned int u32;
typedef unsigned long long u64;
typedef unsigned short u16;

// ---- workspace layout (bytes) ----
#define OFF_META (1ull << 20)                               // T[8] ints; cnt at +4096 (128B-padded per batch)
#define OFF_CAND (OFF_META + 65536ull)                      // B*CAP*8 = 512 KiB
#define OFF_BOXES (OFF_CAND + (unsigned long long)BATCH * CAP * 8ull)
#define OFF_M ((OFF_BOXES + (unsigned long long)BATCH * KPRE * 16ull + 255ull) & ~255ull)
// hist u16 rows (8 MB) live in the M region (dead until k_mask) — no ws growth.

__device__ inline u64 shfl64(u64 v, int src) {
  int lo = __shfl((int)(u32)v, src, 64);
  int hi = __shfl((int)(v >> 32), src, 64);
  return ((u64)(u32)hi << 32) | (u32)lo;
}

// ---- 1: per-block private LDS histogram of score float-bits; flush u16 rows (no global atomics) ----
__global__ __launch_bounds__(1024) void k_hist(const float* __restrict__ probs, u16* __restrict__ histr) {
  __shared__ u32 sh[NBUCKET];  // 128 KiB
  int b = blockIdx.y, blk = blockIdx.x;
  for (int t = threadIdx.x; t < NBUCKET; t += 1024) sh[t] = 0;
  __syncthreads();
  const float4* p4 = (const float4*)(probs + (size_t)b * NANCH * 2);
  const int n4 = NANCH / 2;  // 2 scores per float4
  for (int i = blk * 1024 + threadIdx.x; i < n4; i += HB * 1024) {
    float4 v = p4[i];
    atomicAdd(&sh[__float_as_uint(v.y) >> 15], 1u);
    atomicAdd(&sh[__float_as_uint(v.w) >> 15], 1u);
  }
  __syncthreads();
  u32* dst = (u32*)(histr + ((size_t)b * HB + blk) * NBUCKET);
  for (int t = threadIdx.x; t < NBUCKET / 2; t += 1024)
    dst[t] = (sh[2 * t] & 0xFFFFu) | (sh[2 * t + 1] << 16);
}

// ---- 2: reduce 16 u16 rows, find threshold bucket T ----
__global__ __launch_bounds__(256) void k_thresh(const u16* __restrict__ histr, int* __restrict__ meta) {
  __shared__ int csum[256];
  __shared__ int bt[128];
  __shared__ int s_c, s_sfx;
  int b = blockIdx.x;
  const u16* hb = histr + (size_t)b * HB * NBUCKET;
  int t = threadIdx.x;
  int s = 0;
  for (int r = 0; r < HB; ++r) {
    const uint4* row = (const uint4*)(hb + (size_t)r * NBUCKET + t * 128);
    #pragma unroll
    for (int k = 0; k < 16; ++k) {
      uint4 v = row[k];
      s += (v.x & 0xFFFF) + (v.x >> 16) + (v.y & 0xFFFF) + (v.y >> 16)
         + (v.z & 0xFFFF) + (v.z >> 16) + (v.w & 0xFFFF) + (v.w >> 16);
    }
  }
  csum[t] = s;
  __syncthreads();
  if (t == 0) {
    int suffix = 0, c = 0;
    for (int cc = 255; cc >= 0; --cc) {
      int ns = suffix + csum[cc];
      if (ns >= KPRE) { c = cc; break; }
      suffix = ns;
    }
    s_c = c; s_sfx = suffix;
  }
  __syncthreads();
  int cstar = s_c;
  if (t < 128) {
    int bsum = 0;
    for (int r = 0; r < HB; ++r) bsum += hb[(size_t)r * NBUCKET + cstar * 128 + t];
    bt[t] = bsum;
  }
  __syncthreads();
  if (t == 0) {
    int run = s_sfx, T = 0;
    for (int k = 127; k >= 0; --k) {
      run += bt[k];
      if (run >= KPRE) { T = cstar * 128 + k; break; }
    }
    meta[b] = T;
  }
}

// ---- 3: compact candidates (bucket >= T); hierarchical aggregation: ballot -> LDS -> 1 global atomic/block ----
__global__ __launch_bounds__(256) void k_compact(const float* __restrict__ probs, const int* __restrict__ meta,
                                                 int* __restrict__ cnt, u64* __restrict__ cand) {
  __shared__ int wbase[4];
  __shared__ int btot, bbase;
  int b = blockIdx.y;
  int T = meta[b];
  const int n4 = NANCH / 2;
  int i = blockIdx.x * 256 + threadIdx.x;
  int lane = threadIdx.x & 63, wv = threadIdx.x >> 6;
  if (threadIdx.x == 0) btot = 0;
  __syncthreads();
  u32 bits0 = 0, bits1 = 0;
  bool p0 = false, p1 = false;
  if (i < n4) {
    float4 v = ((const float4*)(probs + (size_t)b * NANCH * 2))[i];
    bits0 = __float_as_uint(v.y); bits1 = __float_as_uint(v.w);
    p0 = (int)(bits0 >> 15) >= T; p1 = (int)(bits1 >> 15) >= T;
  }
  u64 m0 = __ballot(p0);
  u64 m1 = __ballot(p1);
  int c0 = (int)__popcll(m0), c1 = (int)__popcll(m1);
  if (lane == 0) wbase[wv] = (c0 + c1) ? atomicAdd(&btot, c0 + c1) : 0;
  __syncthreads();
  if (threadIdx.x == 0 && btot) bbase = atomicAdd(&cnt[b * 32], btot);
  __syncthreads();
  if (p0 | p1) {
    int base = bbase + wbase[wv];
    if (p0) {
      int pos = base + (int)__popcll(m0 & ((1ull << lane) - 1ull));
      if (pos < CAP) cand[(size_t)b * CAP + pos] = ((u64)bits0 << 32) | (u32)(~(u32)(2 * i));
    }
    if (p1) {
      int pos = base + c0 + (int)__popcll(m1 & ((1ull << lane) - 1ull));
      if (pos < CAP) cand[(size_t)b * CAP + pos] = ((u64)bits1 << 32) | (u32)(~(u32)(2 * i + 1));
    }
  }
}

// ---- 4: bitonic sort (desc) + gather + box decode ----
__global__ __launch_bounds__(1024) void k_sortbox(const u64* __restrict__ cand, const int* __restrict__ cnt,
                                                  const float* __restrict__ anchors, const float* __restrict__ bbox,
                                                  float4* __restrict__ boxes) {
  __shared__ u64 sk[CAP];  // 64 KiB
  int b = blockIdx.x;
  int C = cnt[b * 32]; if (C > CAP) C = CAP;
  for (int r = threadIdx.x; r < CAP; r += 1024)
    sk[r] = (r < (int)C) ? cand[(size_t)b * CAP + r] : 0ull;
  __syncthreads();
  for (int ksz = 2; ksz <= CAP; ksz <<= 1) {
    for (int j = ksz >> 1; j > 0; j >>= 1) {
      #pragma unroll
      for (int p = 0; p < CAP / 1024; ++p) {
        int i = threadIdx.x + p * 1024;
        int ixj = i ^ j;
        if (ixj > i) {
          u64 a = sk[i], c2 = sk[ixj];
          bool up = (i & ksz) == 0;
          if ((a < c2) == up) { sk[i] = c2; sk[ixj] = a; }  // descending overall
        }
      }
      __syncthreads();
    }
  }
  for (int r = threadIdx.x; r < KPRE; r += 1024) {
    u64 key = sk[r];
    u32 idx = ~(u32)key;
    const float4 a  = ((const float4*)anchors)[(size_t)b * NANCH + idx];
    const float4 dr = ((const float4*)bbox)[(size_t)b * NANCH + idx];
    float d0 = __fmul_rn(dr.x, 0.1f), d1 = __fmul_rn(dr.y, 0.1f);
    float d2 = __fmul_rn(dr.z, 0.2f), d3 = __fmul_rn(dr.w, 0.2f);
    float h = __fsub_rn(a.z, a.x);
    float w = __fsub_rn(a.w, a.y);
    float cy = __fadd_rn(a.x, __fmul_rn(0.5f, h));
    float cx = __fadd_rn(a.y, __fmul_rn(0.5f, w));
    cy = __fadd_rn(cy, __fmul_rn(d0, h));
    cx = __fadd_rn(cx, __fmul_rn(d1, w));
    h = __fmul_rn(h, (float)exp((double)d2));
    w = __fmul_rn(w, (float)exp((double)d3));
    float y1 = __fsub_rn(cy, __fmul_rn(0.5f, h));
    float x1 = __fsub_rn(cx, __fmul_rn(0.5f, w));
    float4 o; o.x = y1; o.y = x1; o.z = __fadd_rn(y1, h); o.w = __fadd_rn(x1, w);
    boxes[(size_t)b * KPRE + r] = o;
  }
}

// ---- 5: suppression bitmask M[b][r][w], bit k = (IoU(r, c=w*64+k) > thr) && (c > r) ----
__global__ __launch_bounds__(256) void k_mask(const float4* __restrict__ boxes, u64* __restrict__ M) {
  __shared__ float4 sb[WB * 64];
  __shared__ float  sa[WB * 64];
  int b = blockIdx.z;
  int rowblk = blockIdx.x;   // 0..23 (256 rows each)
  int chunk = blockIdx.y;    // 0..3
  int w0 = chunk * WB;
  int w1 = w0 + WB; if (w1 > MW) w1 = MW;
  int c0 = w0 << 6;
  int ncol = (w1 - w0) << 6;
  const float4* bb = boxes + (size_t)b * KPRE;

  for (int t = threadIdx.x; t < ncol; t += 256) {
    int c = c0 + t;
    float4 v;
    if (c < KPRE) v = bb[c];
    else { v.x = 0.f; v.y = 0.f; v.z = 0.f; v.w = 0.f; }
    sb[t] = v;
    sa[t] = __fmul_rn(__fsub_rn(v.z, v.x), __fsub_rn(v.w, v.y));
  }
  __syncthreads();

  int r = rowblk * 256 + threadIdx.x;
  bool rvalid = r < KPRE;
  float4 br;
  if (rvalid) br = bb[r];
  else { br.x = 0.f; br.y = 0.f; br.z = 0.f; br.w = 0.f; }
  float ar = __fmul_rn(__fsub_rn(br.z, br.x), __fsub_rn(br.w, br.y));
  u64* Mr = M + ((size_t)b * KPRE + (size_t)(rvalid ? r : 0)) * MSTRIDE;

  for (int w = w0; w < w1; ++w) {
    int cbase = w << 6;
    u64 bits = 0;
    if (rvalid && (cbase + 63 > r)) {
      int tb = (w - w0) << 6;
      #pragma unroll 4
      for (int k2 = 0; k2 < 64; ++k2) {
        float4 bc = sb[tb + k2];
        float ac = sa[tb + k2];
        float iy1 = fmaxf(br.x, bc.x);
        float ix1 = fmaxf(br.y, bc.y);
        float iy2 = fminf(br.z, bc.z);
        float ix2 = fminf(br.w, bc.w);
        float ih = fmaxf(__fsub_rn(iy2, iy1), 0.0f);
        float iw = fmaxf(__fsub_rn(ix2, ix1), 0.0f);
        float inter = __fmul_rn(ih, iw);
        float uni = __fsub_rn(__fadd_rn(ar, ac), inter);
        float q = __fdiv_rn(inter, fmaxf(uni, 1e-12f));
        if (q > IOU_THR) bits |= (1ull << k2);
      }
      if (cbase <= r) bits &= ~((r - cbase >= 63) ? ~0ull : ((1ull << (r - cbase + 1)) - 1ull));
    }
    if (rvalid) Mr[w] = bits;
  }
}

// ---- 6: block-parallel greedy NMS scan — one block (4 waves) per batch ----
__global__ __launch_bounds__(256) void k_scan(const u64* __restrict__ M, const float4* __restrict__ boxes,
                                              float4* __restrict__ out) {
  __shared__ u64 xch[2][4];
  __shared__ u64 fin[MW];
  __shared__ int pfx[MW];
  int b = blockIdx.x;
  int tid = threadIdx.x;
  int lane = tid & 63;
  int wv = tid >> 6;
  const u64* Mb = M + (size_t)b * KPRE * MSTRIDE;

  if (tid < MW) fin[tid] = 0ull;

  u64 kw0 = ~0ull, kw1 = ~0ull;
  u64 cur = ~0ull;
  u64 dw = Mb[(size_t)lane * MSTRIDE + 0];
  int count = 0;

  for (int w = 0; w < MW; ++w) {
    int rem = KPRE - (w << 6);
    u64 valid = (rem >= 64) ? ~0ull : ((1ull << rem) - 1ull);
    cur &= valid;

    u64 nz = __ballot(dw != 0ull);
    u64 pend = cur & nz;
    while (pend) {
      int k = (int)__builtin_ctzll(pend);
      u64 d = shfl64(dw, k);
      cur &= ~d;
      pend &= (pend - 1);
      pend &= cur;
    }

    if (tid == 0) fin[w] = cur;
    count += (int)__popcll(cur);
    if (count >= PROP || w == MW - 1) break;

    {
      int r = ((w + 1) << 6) + lane;
      dw = (r < KPRE) ? Mb[(size_t)r * MSTRIDE + (w + 1)] : 0ull;
    }

    bool lactive = (lane < 47) && (2 * lane + 1 >= w + 1);
    ulonglong2 mm[16];
    #pragma unroll
    for (int kk = 0; kk < 16; ++kk) {
      int r = (w << 6) + wv + (kk << 2);
      ulonglong2 t2; t2.x = 0ull; t2.y = 0ull;
      if (lactive && r < KPRE)
        t2 = ((const ulonglong2*)(Mb + (size_t)r * MSTRIDE))[lane];
      mm[kk] = t2;
    }
    #pragma unroll
    for (int kk = 0; kk < 16; ++kk) {
      int k = wv + (kk << 2);
      u64 sel = 0ull - ((cur >> k) & 1ull);
      kw0 &= ~(mm[kk].x & sel);
      kw1 &= ~(mm[kk].y & sel);
    }

    int nw = w + 1;
    if (lane == (nw >> 1)) xch[nw & 1][wv] = (nw & 1) ? kw1 : kw0;
    __syncthreads();
    cur = xch[nw & 1][0] & xch[nw & 1][1] & xch[nw & 1][2] & xch[nw & 1][3];
  }
  __syncthreads();

  if (tid == 0) {
    int s = 0;
    for (int t = 0; t < MW; ++t) { pfx[t] = s; s += (int)__popcll(fin[t]); }
  }
  __syncthreads();

  const float4* bb = boxes + (size_t)b * KPRE;
  float4* ob = out + (size_t)b * PROP;
  if (tid < MW) {
    u64 bits = fin[tid];
    int slot = pfx[tid];
    while (bits && slot < PROP) {
      int k = (int)__builtin_ctzll(bits);
      ob[slot] = bb[(tid << 6) + k];
      ++slot;
      bits &= bits - 1;
    }
  }
}

extern "C" void kernel_launch(void* const* d_in, const int* in_sizes, int n_in,
                              void* d_out, int out_size, void* d_ws, size_t ws_size,
                              hipStream_t stream) {
  const float* probs   = (const float*)d_in[0];
  const float* bbox    = (const float*)d_in[1];
  const float* anchors = (const float*)d_in[2];
  char* ws = (char*)d_ws;
  int* meta   = (int*)(ws + OFF_META);          // T[8]
  int* cnt    = (int*)(ws + OFF_META + 4096);   // cnt[b*32], 128B-padded
  u64* cand   = (u64*)(ws + OFF_CAND);
  float4* boxes = (float4*)(ws + OFF_BOXES);
  u64* M      = (u64*)(ws + OFF_M);
  u16* histr  = (u16*)(ws + OFF_M);             // reuse M region (dead until k_mask)
  float4* out = (float4*)d_out;

  (void)hipMemsetAsync(cnt, 0, 4096, stream);
  (void)hipMemsetAsync(d_out, 0, (size_t)out_size * 4, stream);

  dim3 gh(HB, BATCH);
  k_hist<<<gh, 1024, 0, stream>>>(probs, histr);
  k_thresh<<<BATCH, 256, 0, stream>>>(histr, meta);
  dim3 gc((NANCH / 2 + 255) / 256, BATCH);
  k_compact<<<gc, 256, 0, stream>>>(probs, meta, cnt, cand);
  k_sortbox<<<BATCH, 1024, 0, stream>>>(cand, cnt, anchors, bbox, boxes);
  dim3 gm(24, 4, BATCH);
  k_mask<<<gm, 256, 0, stream>>>(boxes, M);
  k_scan<<<BATCH, 256, 0, stream>>>(M, boxes, out);
}

// Round 6
// 401.966 us; speedup vs baseline: 5.5065x; 1.2037x over previous
//
#include <hip/hip_runtime.h>
#include <hip/hip_bf16.h>

#define BATCH 8
#define NANCH 261888
#define KPRE 6000
#define PROP 2000
#define CAP 8192
#define NBUCKET 32768
#define MW 94       // u64 words per row actually used (94*64 = 6016 >= 6000)
#define MSTRIDE 96  // padded stride in u64 words (16B-aligned ulonglong2 loads)
#define IOU_THR 0.7f
#define WB 12       // mask col-chunk size in words (8 chunks of 12; last covers 10)
#define NTILE 108   // active upper-tri tiles per batch: sum_ch min(24, 3ch+3)
#define HB 16       // histogram blocks per batch

typedef unsigned int u32;
typedef unsigned long long u64;
typedef unsigned short u16;

// ---- workspace layout (bytes) ----
#define OFF_META (1ull << 20)                               // T[8] ints; cnt at +4096 (128B-padded per batch)
#define OFF_CAND (OFF_META + 65536ull)                      // B*CAP*8 = 512 KiB
#define OFF_BOXES (OFF_CAND + (unsigned long long)BATCH * CAP * 8ull)
#define OFF_M ((OFF_BOXES + (unsigned long long)BATCH * KPRE * 16ull + 255ull) & ~255ull)
// hist u16 rows (8 MB) live in the M region (dead until k_mask) — no ws growth.

__device__ inline u64 shfl64(u64 v, int src) {
  int lo = __shfl((int)(u32)v, src, 64);
  int hi = __shfl((int)(v >> 32), src, 64);
  return ((u64)(u32)hi << 32) | (u32)lo;
}

// ---- 1: per-block private LDS histogram of score float-bits; flush u16 rows (no global atomics) ----
__global__ __launch_bounds__(1024) void k_hist(const float* __restrict__ probs, u16* __restrict__ histr) {
  __shared__ u32 sh[NBUCKET];  // 128 KiB
  int b = blockIdx.y, blk = blockIdx.x;
  for (int t = threadIdx.x; t < NBUCKET; t += 1024) sh[t] = 0;
  __syncthreads();
  const float4* p4 = (const float4*)(probs + (size_t)b * NANCH * 2);
  const int n4 = NANCH / 2;  // 2 scores per float4
  for (int i = blk * 1024 + threadIdx.x; i < n4; i += HB * 1024) {
    float4 v = p4[i];
    atomicAdd(&sh[__float_as_uint(v.y) >> 15], 1u);
    atomicAdd(&sh[__float_as_uint(v.w) >> 15], 1u);
  }
  __syncthreads();
  u32* dst = (u32*)(histr + ((size_t)b * HB + blk) * NBUCKET);
  for (int t = threadIdx.x; t < NBUCKET / 2; t += 1024)
    dst[t] = (sh[2 * t] & 0xFFFFu) | (sh[2 * t + 1] << 16);
}

// ---- 2: reduce 16 u16 rows, find threshold bucket T ----
__global__ __launch_bounds__(256) void k_thresh(const u16* __restrict__ histr, int* __restrict__ meta) {
  __shared__ int csum[256];
  __shared__ int bt[128];
  __shared__ int s_c, s_sfx;
  int b = blockIdx.x;
  const u16* hb = histr + (size_t)b * HB * NBUCKET;
  int t = threadIdx.x;
  int s = 0;
  for (int r = 0; r < HB; ++r) {
    const uint4* row = (const uint4*)(hb + (size_t)r * NBUCKET + t * 128);
    #pragma unroll
    for (int k = 0; k < 16; ++k) {
      uint4 v = row[k];
      s += (v.x & 0xFFFF) + (v.x >> 16) + (v.y & 0xFFFF) + (v.y >> 16)
         + (v.z & 0xFFFF) + (v.z >> 16) + (v.w & 0xFFFF) + (v.w >> 16);
    }
  }
  csum[t] = s;
  __syncthreads();
  if (t == 0) {
    int suffix = 0, c = 0;
    for (int cc = 255; cc >= 0; --cc) {
      int ns = suffix + csum[cc];
      if (ns >= KPRE) { c = cc; break; }
      suffix = ns;
    }
    s_c = c; s_sfx = suffix;
  }
  __syncthreads();
  int cstar = s_c;
  if (t < 128) {
    int bsum = 0;
    for (int r = 0; r < HB; ++r) bsum += hb[(size_t)r * NBUCKET + cstar * 128 + t];
    bt[t] = bsum;
  }
  __syncthreads();
  if (t == 0) {
    int run = s_sfx, T = 0;
    for (int k = 127; k >= 0; --k) {
      run += bt[k];
      if (run >= KPRE) { T = cstar * 128 + k; break; }
    }
    meta[b] = T;
  }
}

// ---- 3: compact candidates (bucket >= T); hierarchical aggregation: ballot -> LDS -> 1 global atomic/block ----
__global__ __launch_bounds__(256) void k_compact(const float* __restrict__ probs, const int* __restrict__ meta,
                                                 int* __restrict__ cnt, u64* __restrict__ cand) {
  __shared__ int wbase[4];
  __shared__ int btot, bbase;
  int b = blockIdx.y;
  int T = meta[b];
  const int n4 = NANCH / 2;
  int i = blockIdx.x * 256 + threadIdx.x;
  int lane = threadIdx.x & 63, wv = threadIdx.x >> 6;
  if (threadIdx.x == 0) btot = 0;
  __syncthreads();
  u32 bits0 = 0, bits1 = 0;
  bool p0 = false, p1 = false;
  if (i < n4) {
    float4 v = ((const float4*)(probs + (size_t)b * NANCH * 2))[i];
    bits0 = __float_as_uint(v.y); bits1 = __float_as_uint(v.w);
    p0 = (int)(bits0 >> 15) >= T; p1 = (int)(bits1 >> 15) >= T;
  }
  u64 m0 = __ballot(p0);
  u64 m1 = __ballot(p1);
  int c0 = (int)__popcll(m0), c1 = (int)__popcll(m1);
  if (lane == 0) wbase[wv] = (c0 + c1) ? atomicAdd(&btot, c0 + c1) : 0;
  __syncthreads();
  if (threadIdx.x == 0 && btot) bbase = atomicAdd(&cnt[b * 32], btot);
  __syncthreads();
  if (p0 | p1) {
    int base = bbase + wbase[wv];
    if (p0) {
      int pos = base + (int)__popcll(m0 & ((1ull << lane) - 1ull));
      if (pos < CAP) cand[(size_t)b * CAP + pos] = ((u64)bits0 << 32) | (u32)(~(u32)(2 * i));
    }
    if (p1) {
      int pos = base + c0 + (int)__popcll(m1 & ((1ull << lane) - 1ull));
      if (pos < CAP) cand[(size_t)b * CAP + pos] = ((u64)bits1 << 32) | (u32)(~(u32)(2 * i + 1));
    }
  }
}

// ---- 4: bitonic sort (desc) + gather + box decode ----
__global__ __launch_bounds__(1024) void k_sortbox(const u64* __restrict__ cand, const int* __restrict__ cnt,
                                                  const float* __restrict__ anchors, const float* __restrict__ bbox,
                                                  float4* __restrict__ boxes) {
  __shared__ u64 sk[CAP];  // 64 KiB
  int b = blockIdx.x;
  int C = cnt[b * 32]; if (C > CAP) C = CAP;
  for (int r = threadIdx.x; r < CAP; r += 1024)
    sk[r] = (r < (int)C) ? cand[(size_t)b * CAP + r] : 0ull;
  __syncthreads();
  for (int ksz = 2; ksz <= CAP; ksz <<= 1) {
    for (int j = ksz >> 1; j > 0; j >>= 1) {
      #pragma unroll
      for (int p = 0; p < CAP / 1024; ++p) {
        int i = threadIdx.x + p * 1024;
        int ixj = i ^ j;
        if (ixj > i) {
          u64 a = sk[i], c2 = sk[ixj];
          bool up = (i & ksz) == 0;
          if ((a < c2) == up) { sk[i] = c2; sk[ixj] = a; }  // descending overall
        }
      }
      __syncthreads();
    }
  }
  for (int r = threadIdx.x; r < KPRE; r += 1024) {
    u64 key = sk[r];
    u32 idx = ~(u32)key;
    const float4 a  = ((const float4*)anchors)[(size_t)b * NANCH + idx];
    const float4 dr = ((const float4*)bbox)[(size_t)b * NANCH + idx];
    float d0 = __fmul_rn(dr.x, 0.1f), d1 = __fmul_rn(dr.y, 0.1f);
    float d2 = __fmul_rn(dr.z, 0.2f), d3 = __fmul_rn(dr.w, 0.2f);
    float h = __fsub_rn(a.z, a.x);
    float w = __fsub_rn(a.w, a.y);
    float cy = __fadd_rn(a.x, __fmul_rn(0.5f, h));
    float cx = __fadd_rn(a.y, __fmul_rn(0.5f, w));
    cy = __fadd_rn(cy, __fmul_rn(d0, h));
    cx = __fadd_rn(cx, __fmul_rn(d1, w));
    h = __fmul_rn(h, (float)exp((double)d2));
    w = __fmul_rn(w, (float)exp((double)d3));
    float y1 = __fsub_rn(cy, __fmul_rn(0.5f, h));
    float x1 = __fsub_rn(cx, __fmul_rn(0.5f, w));
    float4 o; o.x = y1; o.y = x1; o.z = __fadd_rn(y1, h); o.w = __fadd_rn(x1, w);
    boxes[(size_t)b * KPRE + r] = o;
  }
}

// ---- 5: suppression bitmask M[b][r][w], bit k = (IoU(r, c=w*64+k) > thr) && (c > r) ----
// Only active upper-triangle tiles launched: per batch, chunk ch has min(24, 3ch+3) rowblocks.
// Below-diagonal M words in never-launched tiles stay garbage — provably never applied by k_scan
// (it only ANDs words >= the row's own diagonal word, all of which live in active tiles).
__global__ __launch_bounds__(256) void k_mask(const float4* __restrict__ boxes, u64* __restrict__ M) {
  __shared__ float4 sb[WB * 64];
  __shared__ float  sa[WB * 64];
  int b = blockIdx.y;
  // decode tile -> (ch, rb)
  int tile = blockIdx.x;
  int ch = 0, base = 0;
  #pragma unroll
  for (int j = 0; j < 8; ++j) {
    int c2 = 3 * (j + 1); if (c2 > 24) c2 = 24;
    if (tile >= base + c2) { base += c2; ch = j + 1; }
  }
  int rb = tile - base;

  int w0 = ch * WB;
  int w1 = w0 + WB; if (w1 > MW) w1 = MW;
  int c0 = w0 << 6;
  int ncol = (w1 - w0) << 6;
  const float4* bb = boxes + (size_t)b * KPRE;

  for (int t = threadIdx.x; t < ncol; t += 256) {
    int c = c0 + t;
    float4 v;
    if (c < KPRE) v = bb[c];
    else { v.x = 0.f; v.y = 0.f; v.z = 0.f; v.w = 0.f; }
    sb[t] = v;
    sa[t] = __fmul_rn(__fsub_rn(v.z, v.x), __fsub_rn(v.w, v.y));
  }
  __syncthreads();

  int r = rb * 256 + threadIdx.x;
  bool rvalid = r < KPRE;
  float4 br;
  if (rvalid) br = bb[r];
  else { br.x = 0.f; br.y = 0.f; br.z = 0.f; br.w = 0.f; }
  float ar = __fmul_rn(__fsub_rn(br.z, br.x), __fsub_rn(br.w, br.y));
  u64* Mr = M + ((size_t)b * KPRE + (size_t)(rvalid ? r : 0)) * MSTRIDE;

  for (int w = w0; w < w1; ++w) {
    int cbase = w << 6;
    u64 bits = 0;
    if (rvalid && (cbase + 63 > r)) {
      int tb = (w - w0) << 6;
      #pragma unroll 4
      for (int k2 = 0; k2 < 64; ++k2) {
        float4 bc = sb[tb + k2];
        float ac = sa[tb + k2];
        float iy1 = fmaxf(br.x, bc.x);
        float ix1 = fmaxf(br.y, bc.y);
        float iy2 = fminf(br.z, bc.z);
        float ix2 = fminf(br.w, bc.w);
        float ih = fmaxf(__fsub_rn(iy2, iy1), 0.0f);
        float iw = fmaxf(__fsub_rn(ix2, ix1), 0.0f);
        float inter = __fmul_rn(ih, iw);
        float uni = __fsub_rn(__fadd_rn(ar, ac), inter);
        float q = __fdiv_rn(inter, fmaxf(uni, 1e-12f));
        if (q > IOU_THR) bits |= (1ull << k2);
      }
      if (cbase <= r) bits &= ~((r - cbase >= 63) ? ~0ull : ((1ull << (r - cbase + 1)) - 1ull));
    }
    if (rvalid) Mr[w] = bits;
  }
}

// ---- 6: block-parallel greedy NMS scan — one block (4 waves) per batch ----
__global__ __launch_bounds__(256) void k_scan(const u64* __restrict__ M, const float4* __restrict__ boxes,
                                              float4* __restrict__ out) {
  __shared__ u64 xch[2][4];
  __shared__ u64 fin[MW];
  __shared__ int pfx[MW];
  int b = blockIdx.x;
  int tid = threadIdx.x;
  int lane = tid & 63;
  int wv = tid >> 6;
  const u64* Mb = M + (size_t)b * KPRE * MSTRIDE;

  if (tid < MW) fin[tid] = 0ull;

  u64 kw0 = ~0ull, kw1 = ~0ull;
  u64 cur = ~0ull;
  u64 dw = Mb[(size_t)lane * MSTRIDE + 0];
  int count = 0;

  for (int w = 0; w < MW; ++w) {
    int rem = KPRE - (w << 6);
    u64 valid = (rem >= 64) ? ~0ull : ((1ull << rem) - 1ull);
    cur &= valid;

    u64 nz = __ballot(dw != 0ull);
    u64 pend = cur & nz;
    while (pend) {
      int k = (int)__builtin_ctzll(pend);
      u64 d = shfl64(dw, k);
      cur &= ~d;
      pend &= (pend - 1);
      pend &= cur;
    }

    if (tid == 0) fin[w] = cur;
    count += (int)__popcll(cur);
    if (count >= PROP || w == MW - 1) break;

    {
      int r = ((w + 1) << 6) + lane;
      dw = (r < KPRE) ? Mb[(size_t)r * MSTRIDE + (w + 1)] : 0ull;
    }

    bool lactive = (lane < 47) && (2 * lane + 1 >= w + 1);
    ulonglong2 mm[16];
    #pragma unroll
    for (int kk = 0; kk < 16; ++kk) {
      int r = (w << 6) + wv + (kk << 2);
      ulonglong2 t2; t2.x = 0ull; t2.y = 0ull;
      if (lactive && r < KPRE)
        t2 = ((const ulonglong2*)(Mb + (size_t)r * MSTRIDE))[lane];
      mm[kk] = t2;
    }
    #pragma unroll
    for (int kk = 0; kk < 16; ++kk) {
      int k = wv + (kk << 2);
      u64 sel = 0ull - ((cur >> k) & 1ull);
      kw0 &= ~(mm[kk].x & sel);
      kw1 &= ~(mm[kk].y & sel);
    }

    int nw = w + 1;
    if (lane == (nw >> 1)) xch[nw & 1][wv] = (nw & 1) ? kw1 : kw0;
    __syncthreads();
    cur = xch[nw & 1][0] & xch[nw & 1][1] & xch[nw & 1][2] & xch[nw & 1][3];
  }
  __syncthreads();

  if (tid == 0) {
    int s = 0;
    for (int t = 0; t < MW; ++t) { pfx[t] = s; s += (int)__popcll(fin[t]); }
  }
  __syncthreads();

  const float4* bb = boxes + (size_t)b * KPRE;
  float4* ob = out + (size_t)b * PROP;
  if (tid < MW) {
    u64 bits = fin[tid];
    int slot = pfx[tid];
    while (bits && slot < PROP) {
      int k = (int)__builtin_ctzll(bits);
      ob[slot] = bb[(tid << 6) + k];
      ++slot;
      bits &= bits - 1;
    }
  }
}

extern "C" void kernel_launch(void* const* d_in, const int* in_sizes, int n_in,
                              void* d_out, int out_size, void* d_ws, size_t ws_size,
                              hipStream_t stream) {
  const float* probs   = (const float*)d_in[0];
  const float* bbox    = (const float*)d_in[1];
  const float* anchors = (const float*)d_in[2];
  char* ws = (char*)d_ws;
  int* meta   = (int*)(ws + OFF_META);          // T[8]
  int* cnt    = (int*)(ws + OFF_META + 4096);   // cnt[b*32], 128B-padded
  u64* cand   = (u64*)(ws + OFF_CAND);
  float4* boxes = (float4*)(ws + OFF_BOXES);
  u64* M      = (u64*)(ws + OFF_M);
  u16* histr  = (u16*)(ws + OFF_M);             // reuse M region (dead until k_mask)
  float4* out = (float4*)d_out;

  (void)hipMemsetAsync(cnt, 0, 4096, stream);
  (void)hipMemsetAsync(d_out, 0, (size_t)out_size * 4, stream);

  dim3 gh(HB, BATCH);
  k_hist<<<gh, 1024, 0, stream>>>(probs, histr);
  k_thresh<<<BATCH, 256, 0, stream>>>(histr, meta);
  dim3 gc((NANCH / 2 + 255) / 256, BATCH);
  k_compact<<<gc, 256, 0, stream>>>(probs, meta, cnt, cand);
  k_sortbox<<<BATCH, 1024, 0, stream>>>(cand, cnt, anchors, bbox, boxes);
  dim3 gm(NTILE, BATCH);
  k_mask<<<gm, 256, 0, stream>>>(boxes, M);
  k_scan<<<BATCH, 256, 0, stream>>>(M, boxes, out);
}

// Round 7
// 302.468 us; speedup vs baseline: 7.3179x; 1.3290x over previous
//
#include <hip/hip_runtime.h>
#include <hip/hip_bf16.h>

#define BATCH 8
#define NANCH 261888
#define KPRE 6000
#define PROP 2000
#define CAP 8192
#define NBUCKET 32768
#define MW 94       // u64 words per row actually used (94*64 = 6016 >= 6000)
#define MSTRIDE 96  // padded stride in u64 words (16B-aligned ulonglong2 loads)
#define WB 12       // mask col-chunk size in words (8 chunks of 12; last covers 10)
#define NTILE 108   // active upper-tri tiles per batch: sum_ch min(24, 3ch+3)
#define HB 16       // histogram blocks per batch

typedef unsigned int u32;
typedef unsigned long long u64;
typedef unsigned short u16;

// ---- workspace layout (bytes) ----
#define OFF_META (1ull << 20)                               // T[8] ints; cnt at +4096 (128B-padded per batch)
#define OFF_CAND (OFF_META + 65536ull)                      // B*CAP*8 = 512 KiB
#define OFF_BOXES (OFF_CAND + (unsigned long long)BATCH * CAP * 8ull)
#define OFF_M ((OFF_BOXES + (unsigned long long)BATCH * KPRE * 16ull + 255ull) & ~255ull)
// hist u16 rows (8 MB) live in the M region (dead until k_mask) — no ws growth.

__device__ inline u64 shfl64(u64 v, int src) {
  int lo = __shfl((int)(u32)v, src, 64);
  int hi = __shfl((int)(v >> 32), src, 64);
  return ((u64)(u32)hi << 32) | (u32)lo;
}

// ---- 1: per-block private LDS histogram of score float-bits; flush u16 rows (no global atomics) ----
__global__ __launch_bounds__(1024) void k_hist(const float* __restrict__ probs, u16* __restrict__ histr) {
  __shared__ u32 sh[NBUCKET];  // 128 KiB
  int b = blockIdx.y, blk = blockIdx.x;
  for (int t = threadIdx.x; t < NBUCKET; t += 1024) sh[t] = 0;
  __syncthreads();
  const float4* p4 = (const float4*)(probs + (size_t)b * NANCH * 2);
  const int n4 = NANCH / 2;  // 2 scores per float4
  for (int i = blk * 1024 + threadIdx.x; i < n4; i += HB * 1024) {
    float4 v = p4[i];
    atomicAdd(&sh[__float_as_uint(v.y) >> 15], 1u);
    atomicAdd(&sh[__float_as_uint(v.w) >> 15], 1u);
  }
  __syncthreads();
  u32* dst = (u32*)(histr + ((size_t)b * HB + blk) * NBUCKET);
  for (int t = threadIdx.x; t < NBUCKET / 2; t += 1024)
    dst[t] = (sh[2 * t] & 0xFFFFu) | (sh[2 * t + 1] << 16);
}

// ---- 2: reduce 16 u16 rows, find threshold bucket T ----
__global__ __launch_bounds__(256) void k_thresh(const u16* __restrict__ histr, int* __restrict__ meta) {
  __shared__ int csum[256];
  __shared__ int bt[128];
  __shared__ int s_c, s_sfx;
  int b = blockIdx.x;
  const u16* hb = histr + (size_t)b * HB * NBUCKET;
  int t = threadIdx.x;
  int s = 0;
  for (int r = 0; r < HB; ++r) {
    const uint4* row = (const uint4*)(hb + (size_t)r * NBUCKET + t * 128);
    #pragma unroll
    for (int k = 0; k < 16; ++k) {
      uint4 v = row[k];
      s += (v.x & 0xFFFF) + (v.x >> 16) + (v.y & 0xFFFF) + (v.y >> 16)
         + (v.z & 0xFFFF) + (v.z >> 16) + (v.w & 0xFFFF) + (v.w >> 16);
    }
  }
  csum[t] = s;
  __syncthreads();
  if (t == 0) {
    int suffix = 0, c = 0;
    for (int cc = 255; cc >= 0; --cc) {
      int ns = suffix + csum[cc];
      if (ns >= KPRE) { c = cc; break; }
      suffix = ns;
    }
    s_c = c; s_sfx = suffix;
  }
  __syncthreads();
  int cstar = s_c;
  if (t < 128) {
    int bsum = 0;
    for (int r = 0; r < HB; ++r) bsum += hb[(size_t)r * NBUCKET + cstar * 128 + t];
    bt[t] = bsum;
  }
  __syncthreads();
  if (t == 0) {
    int run = s_sfx, T = 0;
    for (int k = 127; k >= 0; --k) {
      run += bt[k];
      if (run >= KPRE) { T = cstar * 128 + k; break; }
    }
    meta[b] = T;
  }
}

// ---- 3: compact candidates (bucket >= T); hierarchical aggregation: ballot -> LDS -> 1 global atomic/block ----
__global__ __launch_bounds__(256) void k_compact(const float* __restrict__ probs, const int* __restrict__ meta,
                                                 int* __restrict__ cnt, u64* __restrict__ cand) {
  __shared__ int wbase[4];
  __shared__ int btot, bbase;
  int b = blockIdx.y;
  int T = meta[b];
  const int n4 = NANCH / 2;
  int i = blockIdx.x * 256 + threadIdx.x;
  int lane = threadIdx.x & 63, wv = threadIdx.x >> 6;
  if (threadIdx.x == 0) btot = 0;
  __syncthreads();
  u32 bits0 = 0, bits1 = 0;
  bool p0 = false, p1 = false;
  if (i < n4) {
    float4 v = ((const float4*)(probs + (size_t)b * NANCH * 2))[i];
    bits0 = __float_as_uint(v.y); bits1 = __float_as_uint(v.w);
    p0 = (int)(bits0 >> 15) >= T; p1 = (int)(bits1 >> 15) >= T;
  }
  u64 m0 = __ballot(p0);
  u64 m1 = __ballot(p1);
  int c0 = (int)__popcll(m0), c1 = (int)__popcll(m1);
  if (lane == 0) wbase[wv] = (c0 + c1) ? atomicAdd(&btot, c0 + c1) : 0;
  __syncthreads();
  if (threadIdx.x == 0 && btot) bbase = atomicAdd(&cnt[b * 32], btot);
  __syncthreads();
  if (p0 | p1) {
    int base = bbase + wbase[wv];
    if (p0) {
      int pos = base + (int)__popcll(m0 & ((1ull << lane) - 1ull));
      if (pos < CAP) cand[(size_t)b * CAP + pos] = ((u64)bits0 << 32) | (u32)(~(u32)(2 * i));
    }
    if (p1) {
      int pos = base + c0 + (int)__popcll(m1 & ((1ull << lane) - 1ull));
      if (pos < CAP) cand[(size_t)b * CAP + pos] = ((u64)bits1 << 32) | (u32)(~(u32)(2 * i + 1));
    }
  }
}

// ---- 4a: local bitonic sort of 1024-element runs (desc), 8 runs per batch ----
__global__ __launch_bounds__(1024) void k_lsort(u64* __restrict__ cand, const int* __restrict__ cnt) {
  __shared__ u64 sk[1024];  // 8 KiB
  int b = blockIdx.y, run = blockIdx.x;
  int C = cnt[b * 32];
  int g = run * 1024 + threadIdx.x;
  sk[threadIdx.x] = (g < C) ? cand[(size_t)b * CAP + g] : 0ull;
  __syncthreads();
  for (int ksz = 2; ksz <= 1024; ksz <<= 1) {
    for (int j = ksz >> 1; j > 0; j >>= 1) {
      int i = threadIdx.x;
      int ixj = i ^ j;
      if (ixj > i) {
        u64 a = sk[i], c2 = sk[ixj];
        bool up = (i & ksz) == 0;
        if ((a < c2) == up) { sk[i] = c2; sk[ixj] = a; }  // descending
      }
      __syncthreads();
    }
  }
  cand[(size_t)b * CAP + g] = sk[threadIdx.x];
}

// merge-path partition for DESCENDING unique-ish keys, stable toward X (uses >=)
__device__ inline int mp_search(const u64* X, int n1, const u64* Y, int n2, int d) {
  int lo = d - n2; if (lo < 0) lo = 0;
  int hi = d < n1 ? d : n1;
  while (lo < hi) {
    int m = (lo + hi) >> 1;
    if (X[m] >= Y[d - 1 - m]) lo = m + 1; else hi = m;
  }
  return lo;
}

// ---- 4b: merge 8 sorted 1024-runs -> top-6000, fused gather + box decode ----
__global__ __launch_bounds__(1024) void k_merge(const u64* __restrict__ cand,
                                                const float* __restrict__ anchors, const float* __restrict__ bbox,
                                                float4* __restrict__ boxes) {
  __shared__ u64 A[CAP];   // 64 KiB
  __shared__ u64 Bf[CAP];  // 64 KiB
  int b = blockIdx.x;
  int t = threadIdx.x;
  for (int r = t; r < CAP; r += 1024) A[r] = cand[(size_t)b * CAP + r];
  __syncthreads();
  // round 1: 4 merges (1024,1024) -> Bf
  {
    int m = t >> 8, tt = t & 255;
    const u64* X = A + m * 2048; const u64* Y = X + 1024;
    u64* O = Bf + m * 2048;
    int d = tt * 8;
    int i = mp_search(X, 1024, Y, 1024, d), j = d - i;
    #pragma unroll
    for (int k = 0; k < 8; ++k) {
      bool tx = (i < 1024) && (j >= 1024 || X[i] >= Y[j]);
      O[d + k] = tx ? X[i++] : Y[j++];
    }
  }
  __syncthreads();
  // round 2: 2 merges (2048,2048) -> A
  {
    int m = t >> 9, tt = t & 511;
    const u64* X = Bf + m * 4096; const u64* Y = X + 2048;
    u64* O = A + m * 4096;
    int d = tt * 8;
    int i = mp_search(X, 2048, Y, 2048, d), j = d - i;
    #pragma unroll
    for (int k = 0; k < 8; ++k) {
      bool tx = (i < 2048) && (j >= 2048 || X[i] >= Y[j]);
      O[d + k] = tx ? X[i++] : Y[j++];
    }
  }
  __syncthreads();
  // round 3: final merge (4096,4096), emit only top KPRE with fused gather+decode
  {
    const u64* X = A; const u64* Y = A + 4096;
    int d = t * 8;
    if (d < KPRE) {
      int i = mp_search(X, 4096, Y, 4096, d), j = d - i;
      int lim = KPRE - d; if (lim > 8) lim = 8;
      for (int k = 0; k < lim; ++k) {
        bool tx = (i < 4096) && (j >= 4096 || X[i] >= Y[j]);
        u64 key = tx ? X[i++] : Y[j++];
        u32 idx = ~(u32)key;
        const float4 a  = ((const float4*)anchors)[(size_t)b * NANCH + idx];
        const float4 dr = ((const float4*)bbox)[(size_t)b * NANCH + idx];
        float d0 = __fmul_rn(dr.x, 0.1f), d1 = __fmul_rn(dr.y, 0.1f);
        float d2 = __fmul_rn(dr.z, 0.2f), d3 = __fmul_rn(dr.w, 0.2f);
        float h = __fsub_rn(a.z, a.x);
        float w = __fsub_rn(a.w, a.y);
        float cy = __fadd_rn(a.x, __fmul_rn(0.5f, h));
        float cx = __fadd_rn(a.y, __fmul_rn(0.5f, w));
        cy = __fadd_rn(cy, __fmul_rn(d0, h));
        cx = __fadd_rn(cx, __fmul_rn(d1, w));
        h = __fmul_rn(h, (float)exp((double)d2));
        w = __fmul_rn(w, (float)exp((double)d3));
        float y1 = __fsub_rn(cy, __fmul_rn(0.5f, h));
        float x1 = __fsub_rn(cx, __fmul_rn(0.5f, w));
        float4 o; o.x = y1; o.y = x1; o.z = __fadd_rn(y1, h); o.w = __fadd_rn(x1, w);
        boxes[(size_t)b * KPRE + d + k] = o;
      }
    }
  }
}

// ---- 5: suppression bitmask M[b][r][w], bit k = (IoU(r, c=w*64+k) > thr) && (c > r) ----
// Exact div-free test: RN(inter/un2) > 0.7f  <=>  (double)inter >= MD*(double)un2,
// MD = (double)0.7f + 2^-25 (midpoint; tie rounds up to the even neighbor 0x3F333334).
// MD*un2 exact in double (25+24 mantissa bits); equivalence is bit-exact.
__global__ __launch_bounds__(256) void k_mask(const float4* __restrict__ boxes, u64* __restrict__ M) {
  const double MD = (double)0.7f + 0x1.0p-25;
  __shared__ float4 sb[WB * 64];
  __shared__ float  sa[WB * 64];
  int b = blockIdx.y;
  int tile = blockIdx.x;
  int ch = 0, base = 0;
  #pragma unroll
  for (int j = 0; j < 8; ++j) {
    int c2 = 3 * (j + 1); if (c2 > 24) c2 = 24;
    if (tile >= base + c2) { base += c2; ch = j + 1; }
  }
  int rb = tile - base;

  int w0 = ch * WB;
  int w1 = w0 + WB; if (w1 > MW) w1 = MW;
  int c0 = w0 << 6;
  int ncol = (w1 - w0) << 6;
  const float4* bb = boxes + (size_t)b * KPRE;

  for (int t = threadIdx.x; t < ncol; t += 256) {
    int c = c0 + t;
    float4 v;
    if (c < KPRE) v = bb[c];
    else { v.x = 0.f; v.y = 0.f; v.z = 0.f; v.w = 0.f; }
    sb[t] = v;
    sa[t] = __fmul_rn(__fsub_rn(v.z, v.x), __fsub_rn(v.w, v.y));
  }
  __syncthreads();

  int r = rb * 256 + threadIdx.x;
  bool rvalid = r < KPRE;
  float4 br;
  if (rvalid) br = bb[r];
  else { br.x = 0.f; br.y = 0.f; br.z = 0.f; br.w = 0.f; }
  float ar = __fmul_rn(__fsub_rn(br.z, br.x), __fsub_rn(br.w, br.y));
  u64* Mr = M + ((size_t)b * KPRE + (size_t)(rvalid ? r : 0)) * MSTRIDE;

  for (int w = w0; w < w1; ++w) {
    int cbase = w << 6;
    u64 bits = 0;
    if (rvalid && (cbase + 63 > r)) {
      int tb = (w - w0) << 6;
      u32 blo = 0, bhi = 0;
      #pragma unroll 8
      for (int k2 = 0; k2 < 32; ++k2) {
        float4 bc = sb[tb + k2];
        float ac = sa[tb + k2];
        float iy1 = fmaxf(br.x, bc.x);
        float ix1 = fmaxf(br.y, bc.y);
        float iy2 = fminf(br.z, bc.z);
        float ix2 = fminf(br.w, bc.w);
        float ih = fmaxf(__fsub_rn(iy2, iy1), 0.0f);
        float iw = fmaxf(__fsub_rn(ix2, ix1), 0.0f);
        float inter = __fmul_rn(ih, iw);
        float uni = __fsub_rn(__fadd_rn(ar, ac), inter);
        float un2 = fmaxf(uni, 1e-12f);
        if ((double)inter >= MD * (double)un2) blo |= (1u << k2);
      }
      #pragma unroll 8
      for (int k2 = 0; k2 < 32; ++k2) {
        float4 bc = sb[tb + 32 + k2];
        float ac = sa[tb + 32 + k2];
        float iy1 = fmaxf(br.x, bc.x);
        float ix1 = fmaxf(br.y, bc.y);
        float iy2 = fminf(br.z, bc.z);
        float ix2 = fminf(br.w, bc.w);
        float ih = fmaxf(__fsub_rn(iy2, iy1), 0.0f);
        float iw = fmaxf(__fsub_rn(ix2, ix1), 0.0f);
        float inter = __fmul_rn(ih, iw);
        float uni = __fsub_rn(__fadd_rn(ar, ac), inter);
        float un2 = fmaxf(uni, 1e-12f);
        if ((double)inter >= MD * (double)un2) bhi |= (1u << k2);
      }
      bits = (u64)blo | ((u64)bhi << 32);
      if (cbase <= r) bits &= ~((r - cbase >= 63) ? ~0ull : ((1ull << (r - cbase + 1)) - 1ull));
    }
    if (rvalid) Mr[w] = bits;
  }
}

// ---- 6: block-parallel greedy NMS scan — one block (4 waves) per batch ----
__global__ __launch_bounds__(256) void k_scan(const u64* __restrict__ M, const float4* __restrict__ boxes,
                                              float4* __restrict__ out) {
  __shared__ u64 xch[2][4];
  __shared__ u64 fin[MW];
  __shared__ int pfx[MW];
  int b = blockIdx.x;
  int tid = threadIdx.x;
  int lane = tid & 63;
  int wv = tid >> 6;
  const u64* Mb = M + (size_t)b * KPRE * MSTRIDE;

  if (tid < MW) fin[tid] = 0ull;

  u64 kw0 = ~0ull, kw1 = ~0ull;
  u64 cur = ~0ull;
  u64 dw = Mb[(size_t)lane * MSTRIDE + 0];
  int count = 0;

  for (int w = 0; w < MW; ++w) {
    int rem = KPRE - (w << 6);
    u64 valid = (rem >= 64) ? ~0ull : ((1ull << rem) - 1ull);
    cur &= valid;

    u64 nz = __ballot(dw != 0ull);
    u64 pend = cur & nz;
    while (pend) {
      int k = (int)__builtin_ctzll(pend);
      u64 d = shfl64(dw, k);
      cur &= ~d;
      pend &= (pend - 1);
      pend &= cur;
    }

    if (tid == 0) fin[w] = cur;
    count += (int)__popcll(cur);
    if (count >= PROP || w == MW - 1) break;

    {
      int r = ((w + 1) << 6) + lane;
      dw = (r < KPRE) ? Mb[(size_t)r * MSTRIDE + (w + 1)] : 0ull;
    }

    bool lactive = (lane < 47) && (2 * lane + 1 >= w + 1);
    ulonglong2 mm[16];
    #pragma unroll
    for (int kk = 0; kk < 16; ++kk) {
      int r = (w << 6) + wv + (kk << 2);
      ulonglong2 t2; t2.x = 0ull; t2.y = 0ull;
      if (lactive && r < KPRE)
        t2 = ((const ulonglong2*)(Mb + (size_t)r * MSTRIDE))[lane];
      mm[kk] = t2;
    }
    #pragma unroll
    for (int kk = 0; kk < 16; ++kk) {
      int k = wv + (kk << 2);
      u64 sel = 0ull - ((cur >> k) & 1ull);
      kw0 &= ~(mm[kk].x & sel);
      kw1 &= ~(mm[kk].y & sel);
    }

    int nw = w + 1;
    if (lane == (nw >> 1)) xch[nw & 1][wv] = (nw & 1) ? kw1 : kw0;
    __syncthreads();
    cur = xch[nw & 1][0] & xch[nw & 1][1] & xch[nw & 1][2] & xch[nw & 1][3];
  }
  __syncthreads();

  if (tid == 0) {
    int s = 0;
    for (int t = 0; t < MW; ++t) { pfx[t] = s; s += (int)__popcll(fin[t]); }
  }
  __syncthreads();

  const float4* bb = boxes + (size_t)b * KPRE;
  float4* ob = out + (size_t)b * PROP;
  if (tid < MW) {
    u64 bits = fin[tid];
    int slot = pfx[tid];
    while (bits && slot < PROP) {
      int k = (int)__builtin_ctzll(bits);
      ob[slot] = bb[(tid << 6) + k];
      ++slot;
      bits &= bits - 1;
    }
  }
}

extern "C" void kernel_launch(void* const* d_in, const int* in_sizes, int n_in,
                              void* d_out, int out_size, void* d_ws, size_t ws_size,
                              hipStream_t stream) {
  const float* probs   = (const float*)d_in[0];
  const float* bbox    = (const float*)d_in[1];
  const float* anchors = (const float*)d_in[2];
  char* ws = (char*)d_ws;
  int* meta   = (int*)(ws + OFF_META);          // T[8]
  int* cnt    = (int*)(ws + OFF_META + 4096);   // cnt[b*32], 128B-padded
  u64* cand   = (u64*)(ws + OFF_CAND);
  float4* boxes = (float4*)(ws + OFF_BOXES);
  u64* M      = (u64*)(ws + OFF_M);
  u16* histr  = (u16*)(ws + OFF_M);             // reuse M region (dead until k_mask)
  float4* out = (float4*)d_out;

  (void)hipMemsetAsync(cnt, 0, 4096, stream);
  (void)hipMemsetAsync(d_out, 0, (size_t)out_size * 4, stream);

  dim3 gh(HB, BATCH);
  k_hist<<<gh, 1024, 0, stream>>>(probs, histr);
  k_thresh<<<BATCH, 256, 0, stream>>>(histr, meta);
  dim3 gc((NANCH / 2 + 255) / 256, BATCH);
  k_compact<<<gc, 256, 0, stream>>>(probs, meta, cnt, cand);
  dim3 gl(8, BATCH);
  k_lsort<<<gl, 1024, 0, stream>>>(cand, cnt);
  k_merge<<<BATCH, 1024, 0, stream>>>(cand, anchors, bbox, boxes);
  dim3 gm(NTILE, BATCH);
  k_mask<<<gm, 256, 0, stream>>>(boxes, M);
  k_scan<<<BATCH, 256, 0, stream>>>(M, boxes, out);
}

// Round 8
// 247.696 us; speedup vs baseline: 8.9361x; 1.2211x over previous
//
#include <hip/hip_runtime.h>
#include <hip/hip_bf16.h>

#define BATCH 8
#define NANCH 261888
#define KPRE 6000
#define PROP 2000
#define CAP 8192
#define NBUCKET 32768
#define MW 94       // u64 words per row actually used (94*64 = 6016 >= 6000)
#define MSTRIDE 96  // padded stride in u64 words; rows are 768B, 64B-aligned
#define WB 8        // mask col-chunk = 8 words = one 64B line per row per block
#define NCH 12      // 12 chunks of 8 words cover 94 (+2 pad words 94,95)
#define NTILE 156   // per batch: sum_{ch=0..11} (2ch+2)
#define HB 16       // histogram blocks per batch

typedef unsigned int u32;
typedef unsigned long long u64;
typedef unsigned short u16;

// ---- workspace layout (bytes) ----
#define OFF_META (1ull << 20)   // +0: T[8]; +4096: cnt[b*32] (128B-padded); +8192: coarse u32[8][256]
#define OFF_CAND (OFF_META + 65536ull)                      // B*CAP*8 = 512 KiB
#define OFF_BOXES (OFF_CAND + (unsigned long long)BATCH * CAP * 8ull)
#define OFF_M ((OFF_BOXES + (unsigned long long)BATCH * KPRE * 16ull + 255ull) & ~255ull)
// hist u16 rows (8 MB) live in the M region (dead until k_mask) — no ws growth.

__device__ inline u64 shfl64(u64 v, int src) {
  int lo = __shfl((int)(u32)v, src, 64);
  int hi = __shfl((int)(v >> 32), src, 64);
  return ((u64)(u32)hi << 32) | (u32)lo;
}

// ---- 1: per-block private LDS histogram; flush u16 row + 256-bin coarse atomics ----
__global__ __launch_bounds__(1024) void k_hist(const float* __restrict__ probs, u16* __restrict__ histr,
                                               u32* __restrict__ coarse) {
  __shared__ u32 sh[NBUCKET];  // 128 KiB
  int b = blockIdx.y, blk = blockIdx.x;
  for (int t = threadIdx.x; t < NBUCKET; t += 1024) sh[t] = 0;
  __syncthreads();
  const float4* p4 = (const float4*)(probs + (size_t)b * NANCH * 2);
  const int n4 = NANCH / 2;  // 2 scores per float4
  for (int i = blk * 1024 + threadIdx.x; i < n4; i += HB * 1024) {
    float4 v = p4[i];
    atomicAdd(&sh[__float_as_uint(v.y) >> 15], 1u);
    atomicAdd(&sh[__float_as_uint(v.w) >> 15], 1u);
  }
  __syncthreads();
  u32* dst = (u32*)(histr + ((size_t)b * HB + blk) * NBUCKET);
  for (int t = threadIdx.x; t < NBUCKET / 2; t += 1024)
    dst[t] = (sh[2 * t] & 0xFFFFu) | (sh[2 * t + 1] << 16);
  // coarse 256-bin: thread t sums its 128-bucket chunk (rotated start -> no bank conflicts)
  if (threadIdx.x < 256) {
    int t = threadIdx.x;
    u32 s = 0;
    #pragma unroll 8
    for (int i = 0; i < 128; ++i) s += sh[128 * t + ((i + t) & 127)];
    if (s) atomicAdd(&coarse[b * 256 + t], s);
  }
}

// ---- 2: find threshold bucket T from coarse (1KB) + one fine chunk (4KB) ----
__global__ __launch_bounds__(256) void k_thresh(const u16* __restrict__ histr, const u32* __restrict__ coarse,
                                                int* __restrict__ meta) {
  __shared__ u32 cg[256];
  __shared__ int bt[128];
  __shared__ int s_c, s_sfx;
  int b = blockIdx.x;
  int t = threadIdx.x;
  cg[t] = coarse[b * 256 + t];
  __syncthreads();
  if (t == 0) {
    int suffix = 0, c = 0;
    for (int cc = 255; cc >= 0; --cc) {
      int ns = suffix + (int)cg[cc];
      if (ns >= KPRE) { c = cc; break; }
      suffix = ns;
    }
    s_c = c; s_sfx = suffix;
  }
  __syncthreads();
  int cstar = s_c;
  if (t < 128) {
    const u16* hb = histr + (size_t)b * HB * NBUCKET;
    int bsum = 0;
    for (int r = 0; r < HB; ++r) bsum += hb[(size_t)r * NBUCKET + cstar * 128 + t];
    bt[t] = bsum;
  }
  __syncthreads();
  if (t == 0) {
    int run = s_sfx, T = 0;
    for (int k = 127; k >= 0; --k) {
      run += bt[k];
      if (run >= KPRE) { T = cstar * 128 + k; break; }
    }
    meta[b] = T;
  }
}

// ---- 3: compact candidates (bucket >= T); ballot -> LDS -> 1 global atomic/block ----
__global__ __launch_bounds__(256) void k_compact(const float* __restrict__ probs, const int* __restrict__ meta,
                                                 int* __restrict__ cnt, u64* __restrict__ cand) {
  __shared__ int wbase[4];
  __shared__ int btot, bbase;
  int b = blockIdx.y;
  int T = meta[b];
  const int n4 = NANCH / 2;
  int i = blockIdx.x * 256 + threadIdx.x;
  int lane = threadIdx.x & 63, wv = threadIdx.x >> 6;
  if (threadIdx.x == 0) btot = 0;
  __syncthreads();
  u32 bits0 = 0, bits1 = 0;
  bool p0 = false, p1 = false;
  if (i < n4) {
    float4 v = ((const float4*)(probs + (size_t)b * NANCH * 2))[i];
    bits0 = __float_as_uint(v.y); bits1 = __float_as_uint(v.w);
    p0 = (int)(bits0 >> 15) >= T; p1 = (int)(bits1 >> 15) >= T;
  }
  u64 m0 = __ballot(p0);
  u64 m1 = __ballot(p1);
  int c0 = (int)__popcll(m0), c1 = (int)__popcll(m1);
  if (lane == 0) wbase[wv] = (c0 + c1) ? atomicAdd(&btot, c0 + c1) : 0;
  __syncthreads();
  if (threadIdx.x == 0 && btot) bbase = atomicAdd(&cnt[b * 32], btot);
  __syncthreads();
  if (p0 | p1) {
    int base = bbase + wbase[wv];
    if (p0) {
      int pos = base + (int)__popcll(m0 & ((1ull << lane) - 1ull));
      if (pos < CAP) cand[(size_t)b * CAP + pos] = ((u64)bits0 << 32) | (u32)(~(u32)(2 * i));
    }
    if (p1) {
      int pos = base + c0 + (int)__popcll(m1 & ((1ull << lane) - 1ull));
      if (pos < CAP) cand[(size_t)b * CAP + pos] = ((u64)bits1 << 32) | (u32)(~(u32)(2 * i + 1));
    }
  }
}

// ---- 4a: local bitonic sort of 1024-element runs (desc), 8 runs per batch ----
__global__ __launch_bounds__(1024) void k_lsort(u64* __restrict__ cand, const int* __restrict__ cnt) {
  __shared__ u64 sk[1024];  // 8 KiB
  int b = blockIdx.y, run = blockIdx.x;
  int C = cnt[b * 32];
  int g = run * 1024 + threadIdx.x;
  sk[threadIdx.x] = (g < C) ? cand[(size_t)b * CAP + g] : 0ull;
  __syncthreads();
  for (int ksz = 2; ksz <= 1024; ksz <<= 1) {
    for (int j = ksz >> 1; j > 0; j >>= 1) {
      int i = threadIdx.x;
      int ixj = i ^ j;
      if (ixj > i) {
        u64 a = sk[i], c2 = sk[ixj];
        bool up = (i & ksz) == 0;
        if ((a < c2) == up) { sk[i] = c2; sk[ixj] = a; }  // descending
      }
      __syncthreads();
    }
  }
  cand[(size_t)b * CAP + g] = sk[threadIdx.x];
}

// merge-path partition for DESCENDING keys, stable toward X (uses >=)
__device__ inline int mp_search(const u64* X, int n1, const u64* Y, int n2, int d) {
  int lo = d - n2; if (lo < 0) lo = 0;
  int hi = d < n1 ? d : n1;
  while (lo < hi) {
    int m = (lo + hi) >> 1;
    if (X[m] >= Y[d - 1 - m]) lo = m + 1; else hi = m;
  }
  return lo;
}

// ---- 4b: merge 8 sorted 1024-runs -> top-6000, fused gather + box decode ----
__global__ __launch_bounds__(1024) void k_merge(const u64* __restrict__ cand,
                                                const float* __restrict__ anchors, const float* __restrict__ bbox,
                                                float4* __restrict__ boxes) {
  __shared__ u64 A[CAP];   // 64 KiB
  __shared__ u64 Bf[CAP];  // 64 KiB
  int b = blockIdx.x;
  int t = threadIdx.x;
  for (int r = t; r < CAP; r += 1024) A[r] = cand[(size_t)b * CAP + r];
  __syncthreads();
  {
    int m = t >> 8, tt = t & 255;
    const u64* X = A + m * 2048; const u64* Y = X + 1024;
    u64* O = Bf + m * 2048;
    int d = tt * 8;
    int i = mp_search(X, 1024, Y, 1024, d), j = d - i;
    #pragma unroll
    for (int k = 0; k < 8; ++k) {
      bool tx = (i < 1024) && (j >= 1024 || X[i] >= Y[j]);
      O[d + k] = tx ? X[i++] : Y[j++];
    }
  }
  __syncthreads();
  {
    int m = t >> 9, tt = t & 511;
    const u64* X = Bf + m * 4096; const u64* Y = X + 2048;
    u64* O = A + m * 4096;
    int d = tt * 8;
    int i = mp_search(X, 2048, Y, 2048, d), j = d - i;
    #pragma unroll
    for (int k = 0; k < 8; ++k) {
      bool tx = (i < 2048) && (j >= 2048 || X[i] >= Y[j]);
      O[d + k] = tx ? X[i++] : Y[j++];
    }
  }
  __syncthreads();
  {
    const u64* X = A; const u64* Y = A + 4096;
    int d = t * 8;
    if (d < KPRE) {
      int i = mp_search(X, 4096, Y, 4096, d), j = d - i;
      int lim = KPRE - d; if (lim > 8) lim = 8;
      for (int k = 0; k < lim; ++k) {
        bool tx = (i < 4096) && (j >= 4096 || X[i] >= Y[j]);
        u64 key = tx ? X[i++] : Y[j++];
        u32 idx = ~(u32)key;
        const float4 a  = ((const float4*)anchors)[(size_t)b * NANCH + idx];
        const float4 dr = ((const float4*)bbox)[(size_t)b * NANCH + idx];
        float d0 = __fmul_rn(dr.x, 0.1f), d1 = __fmul_rn(dr.y, 0.1f);
        float d2 = __fmul_rn(dr.z, 0.2f), d3 = __fmul_rn(dr.w, 0.2f);
        float h = __fsub_rn(a.z, a.x);
        float w = __fsub_rn(a.w, a.y);
        float cy = __fadd_rn(a.x, __fmul_rn(0.5f, h));
        float cx = __fadd_rn(a.y, __fmul_rn(0.5f, w));
        cy = __fadd_rn(cy, __fmul_rn(d0, h));
        cx = __fadd_rn(cx, __fmul_rn(d1, w));
        h = __fmul_rn(h, (float)exp((double)d2));
        w = __fmul_rn(w, (float)exp((double)d3));
        float y1 = __fsub_rn(cy, __fmul_rn(0.5f, h));
        float x1 = __fsub_rn(cx, __fmul_rn(0.5f, w));
        float4 o; o.x = y1; o.y = x1; o.z = __fadd_rn(y1, h); o.w = __fadd_rn(x1, w);
        boxes[(size_t)b * KPRE + d + k] = o;
      }
    }
  }
}

// ---- 5: suppression bitmask M[b][r][w], bit k = (IoU(r, c=w*64+k) > thr) && (c > r) ----
// Exact div-free: RN(inter/uni) > 0.7f <=> (double)inter >= MD*(double)uni, MD = (double)0.7f + 2^-25.
// fmax(uni,1e-12) dropped: areas >= ~5e-5 (anchors h,w >= 0.01, bounded deltas) so uni >> 1e-12 always.
// Each block: one 8-word (64B) chunk x 256 rows; full-line register-buffered stores (no L2 RMW).
__global__ __launch_bounds__(256) void k_mask(const float4* __restrict__ boxes, u64* __restrict__ M) {
  const double MD = (double)0.7f + 0x1.0p-25;
  __shared__ float4 sb[WB * 64];
  __shared__ float  sa[WB * 64];
  int b = blockIdx.y;
  int tile = NTILE - 1 - blockIdx.x;  // heavy tiles dispatched first
  int ch = 0, base = 0;
  #pragma unroll
  for (int j = 0; j < NCH; ++j) {
    int n = 2 * j + 2;
    if (tile >= base + n) { base += n; ch = j + 1; }
  }
  int rb = tile - base;

  int w0 = ch * WB;
  int w1 = w0 + WB; if (w1 > MW) w1 = MW;
  int c0 = w0 << 6;
  int ncol = (w1 - w0) << 6;
  const float4* bb = boxes + (size_t)b * KPRE;

  for (int t = threadIdx.x; t < ncol; t += 256) {
    int c = c0 + t;
    float4 v;
    if (c < KPRE) v = bb[c];
    else { v.x = 0.f; v.y = 0.f; v.z = 0.f; v.w = 0.f; }
    sb[t] = v;
    sa[t] = __fmul_rn(__fsub_rn(v.z, v.x), __fsub_rn(v.w, v.y));
  }
  __syncthreads();

  int r = rb * 256 + threadIdx.x;
  bool rvalid = r < KPRE;
  float4 br;
  if (rvalid) br = bb[rvalid ? r : 0];
  else { br.x = 0.f; br.y = 0.f; br.z = 0.f; br.w = 0.f; }
  float ar = __fmul_rn(__fsub_rn(br.z, br.x), __fsub_rn(br.w, br.y));
  u64* Mr = M + ((size_t)b * KPRE + (size_t)(rvalid ? r : 0)) * MSTRIDE;

  u64 wbuf[WB];
  #pragma unroll
  for (int k = 0; k < WB; ++k) {
    int w = w0 + k;
    int cbase = w << 6;
    u64 bits = 0ull;
    if (rvalid && (w < MW) && (cbase + 63 > r)) {
      int tb = k << 6;
      u32 blo = 0, bhi = 0;
      #pragma unroll 8
      for (int k2 = 0; k2 < 32; ++k2) {
        float4 bc = sb[tb + k2];
        float ac = sa[tb + k2];
        float iy1 = fmaxf(br.x, bc.x);
        float ix1 = fmaxf(br.y, bc.y);
        float iy2 = fminf(br.z, bc.z);
        float ix2 = fminf(br.w, bc.w);
        float ih = fmaxf(__fsub_rn(iy2, iy1), 0.0f);
        float iw = fmaxf(__fsub_rn(ix2, ix1), 0.0f);
        float inter = __fmul_rn(ih, iw);
        float uni = __fsub_rn(__fadd_rn(ar, ac), inter);
        if ((double)inter >= MD * (double)uni) blo |= (1u << k2);
      }
      #pragma unroll 8
      for (int k2 = 0; k2 < 32; ++k2) {
        float4 bc = sb[tb + 32 + k2];
        float ac = sa[tb + 32 + k2];
        float iy1 = fmaxf(br.x, bc.x);
        float ix1 = fmaxf(br.y, bc.y);
        float iy2 = fminf(br.z, bc.z);
        float ix2 = fminf(br.w, bc.w);
        float ih = fmaxf(__fsub_rn(iy2, iy1), 0.0f);
        float iw = fmaxf(__fsub_rn(ix2, ix1), 0.0f);
        float inter = __fmul_rn(ih, iw);
        float uni = __fsub_rn(__fadd_rn(ar, ac), inter);
        if ((double)inter >= MD * (double)uni) bhi |= (1u << k2);
      }
      bits = (u64)blo | ((u64)bhi << 32);
      if (cbase <= r) bits &= ~((r - cbase >= 63) ? ~0ull : ((1ull << (r - cbase + 1)) - 1ull));
    }
    wbuf[k] = bits;
  }
  if (rvalid) {
    ulonglong2* dst = (ulonglong2*)(Mr + w0);  // 64B-aligned (w0 even, rows 768B)
    #pragma unroll
    for (int k = 0; k < WB / 2; ++k) {
      ulonglong2 v; v.x = wbuf[2 * k]; v.y = wbuf[2 * k + 1];
      dst[k] = v;
    }
  }
}

// ---- 6: block-parallel greedy NMS scan — one block (4 waves) per batch ----
__global__ __launch_bounds__(256) void k_scan(const u64* __restrict__ M, const float4* __restrict__ boxes,
                                              float4* __restrict__ out) {
  __shared__ u64 xch[2][4];
  __shared__ u64 fin[MW];
  __shared__ int pfx[MW];
  int b = blockIdx.x;
  int tid = threadIdx.x;
  int lane = tid & 63;
  int wv = tid >> 6;
  const u64* Mb = M + (size_t)b * KPRE * MSTRIDE;

  if (tid < MW) fin[tid] = 0ull;

  u64 kw0 = ~0ull, kw1 = ~0ull;
  u64 cur = ~0ull;
  u64 dw = Mb[(size_t)lane * MSTRIDE + 0];
  int count = 0;

  for (int w = 0; w < MW; ++w) {
    int rem = KPRE - (w << 6);
    u64 valid = (rem >= 64) ? ~0ull : ((1ull << rem) - 1ull);
    cur &= valid;

    u64 nz = __ballot(dw != 0ull);
    u64 pend = cur & nz;
    while (pend) {
      int k = (int)__builtin_ctzll(pend);
      u64 d = shfl64(dw, k);
      cur &= ~d;
      pend &= (pend - 1);
      pend &= cur;
    }

    if (tid == 0) fin[w] = cur;
    count += (int)__popcll(cur);
    if (count >= PROP || w == MW - 1) break;

    {
      int r = ((w + 1) << 6) + lane;
      dw = (r < KPRE) ? Mb[(size_t)r * MSTRIDE + (w + 1)] : 0ull;
    }

    bool lactive = (lane < 47) && (2 * lane + 1 >= w + 1);
    ulonglong2 mm[16];
    #pragma unroll
    for (int kk = 0; kk < 16; ++kk) {
      int r = (w << 6) + wv + (kk << 2);
      ulonglong2 t2; t2.x = 0ull; t2.y = 0ull;
      if (lactive && r < KPRE)
        t2 = ((const ulonglong2*)(Mb + (size_t)r * MSTRIDE))[lane];
      mm[kk] = t2;
    }
    #pragma unroll
    for (int kk = 0; kk < 16; ++kk) {
      int k = wv + (kk << 2);
      u64 sel = 0ull - ((cur >> k) & 1ull);
      kw0 &= ~(mm[kk].x & sel);
      kw1 &= ~(mm[kk].y & sel);
    }

    int nw = w + 1;
    if (lane == (nw >> 1)) xch[nw & 1][wv] = (nw & 1) ? kw1 : kw0;
    __syncthreads();
    cur = xch[nw & 1][0] & xch[nw & 1][1] & xch[nw & 1][2] & xch[nw & 1][3];
  }
  __syncthreads();

  if (tid == 0) {
    int s = 0;
    for (int t = 0; t < MW; ++t) { pfx[t] = s; s += (int)__popcll(fin[t]); }
  }
  __syncthreads();

  const float4* bb = boxes + (size_t)b * KPRE;
  float4* ob = out + (size_t)b * PROP;
  if (tid < MW) {
    u64 bits = fin[tid];
    int slot = pfx[tid];
    while (bits && slot < PROP) {
      int k = (int)__builtin_ctzll(bits);
      ob[slot] = bb[(tid << 6) + k];
      ++slot;
      bits &= bits - 1;
    }
  }
}

extern "C" void kernel_launch(void* const* d_in, const int* in_sizes, int n_in,
                              void* d_out, int out_size, void* d_ws, size_t ws_size,
                              hipStream_t stream) {
  const float* probs   = (const float*)d_in[0];
  const float* bbox    = (const float*)d_in[1];
  const float* anchors = (const float*)d_in[2];
  char* ws = (char*)d_ws;
  int* meta    = (int*)(ws + OFF_META);          // T[8]
  int* cnt     = (int*)(ws + OFF_META + 4096);   // cnt[b*32], 128B-padded
  u32* coarse  = (u32*)(ws + OFF_META + 8192);   // u32[8][256]
  u64* cand    = (u64*)(ws + OFF_CAND);
  float4* boxes = (float4*)(ws + OFF_BOXES);
  u64* M       = (u64*)(ws + OFF_M);
  u16* histr   = (u16*)(ws + OFF_M);             // reuse M region (dead until k_mask)
  float4* out  = (float4*)d_out;

  (void)hipMemsetAsync(ws + OFF_META + 4096, 0, 12288, stream);  // cnt + coarse
  (void)hipMemsetAsync(d_out, 0, (size_t)out_size * 4, stream);

  dim3 gh(HB, BATCH);
  k_hist<<<gh, 1024, 0, stream>>>(probs, histr, coarse);
  k_thresh<<<BATCH, 256, 0, stream>>>(histr, coarse, meta);
  dim3 gc((NANCH / 2 + 255) / 256, BATCH);
  k_compact<<<gc, 256, 0, stream>>>(probs, meta, cnt, cand);
  dim3 gl(8, BATCH);
  k_lsort<<<gl, 1024, 0, stream>>>(cand, cnt);
  k_merge<<<BATCH, 1024, 0, stream>>>(cand, anchors, bbox, boxes);
  dim3 gm(NTILE, BATCH);
  k_mask<<<gm, 256, 0, stream>>>(boxes, M);
  k_scan<<<BATCH, 256, 0, stream>>>(M, boxes, out);
}

// Round 9
// 244.270 us; speedup vs baseline: 9.0615x; 1.0140x over previous
//
#include <hip/hip_runtime.h>
#include <hip/hip_bf16.h>

#define BATCH 8
#define NANCH 261888
#define KPRE 6000
#define PROP 2000
#define CAP 8192
#define NBUCKET 32768
#define MW 94       // u64 words per row actually used (94*64 = 6016 >= 6000)
#define MSTRIDE 96  // padded stride in u64 words; rows are 768B, 64B-aligned
#define WB 8        // mask col-chunk = 8 words = one 64B line per row per block
#define NCH 12      // 12 chunks of 8 words cover 94 (+2 pad words 94,95)
#define NTILE 156   // per batch: sum_{ch=0..10} 2(ch+1) + 24 = 132 + 24
#define HB 16       // histogram blocks per batch

typedef unsigned int u32;
typedef unsigned long long u64;
typedef unsigned short u16;

// ---- workspace layout (bytes) ----
#define OFF_META (1ull << 20)   // +0: T[8]; +4096: cnt[b*32] (128B-padded); +8192: coarse u32[8][256]
#define OFF_CAND (OFF_META + 65536ull)                      // B*CAP*8 = 512 KiB
#define OFF_BOXES (OFF_CAND + (unsigned long long)BATCH * CAP * 8ull)
#define OFF_M ((OFF_BOXES + (unsigned long long)BATCH * KPRE * 16ull + 255ull) & ~255ull)
// hist u16 rows (8 MB) live in the M region (dead until k_mask) — no ws growth.

__device__ inline u64 shfl64(u64 v, int src) {
  int lo = __shfl((int)(u32)v, src, 64);
  int hi = __shfl((int)(v >> 32), src, 64);
  return ((u64)(u32)hi << 32) | (u32)lo;
}

// ---- 1: per-block private LDS histogram; flush u16 row + 256-bin coarse atomics ----
__global__ __launch_bounds__(1024) void k_hist(const float* __restrict__ probs, u16* __restrict__ histr,
                                               u32* __restrict__ coarse) {
  __shared__ u32 sh[NBUCKET];  // 128 KiB
  int b = blockIdx.y, blk = blockIdx.x;
  for (int t = threadIdx.x; t < NBUCKET; t += 1024) sh[t] = 0;
  __syncthreads();
  const float4* p4 = (const float4*)(probs + (size_t)b * NANCH * 2);
  const int n4 = NANCH / 2;  // 2 scores per float4
  for (int i = blk * 1024 + threadIdx.x; i < n4; i += HB * 1024) {
    float4 v = p4[i];
    atomicAdd(&sh[__float_as_uint(v.y) >> 15], 1u);
    atomicAdd(&sh[__float_as_uint(v.w) >> 15], 1u);
  }
  __syncthreads();
  u32* dst = (u32*)(histr + ((size_t)b * HB + blk) * NBUCKET);
  for (int t = threadIdx.x; t < NBUCKET / 2; t += 1024)
    dst[t] = (sh[2 * t] & 0xFFFFu) | (sh[2 * t + 1] << 16);
  // coarse 256-bin: thread t sums its 128-bucket chunk (rotated start -> no bank conflicts)
  if (threadIdx.x < 256) {
    int t = threadIdx.x;
    u32 s = 0;
    #pragma unroll 8
    for (int i = 0; i < 128; ++i) s += sh[128 * t + ((i + t) & 127)];
    if (s) atomicAdd(&coarse[b * 256 + t], s);
  }
}

// ---- 2: find threshold bucket T from coarse (1KB) + one fine chunk (4KB) ----
__global__ __launch_bounds__(256) void k_thresh(const u16* __restrict__ histr, const u32* __restrict__ coarse,
                                                int* __restrict__ meta) {
  __shared__ u32 cg[256];
  __shared__ int bt[128];
  __shared__ int s_c, s_sfx;
  int b = blockIdx.x;
  int t = threadIdx.x;
  cg[t] = coarse[b * 256 + t];
  __syncthreads();
  if (t == 0) {
    int suffix = 0, c = 0;
    for (int cc = 255; cc >= 0; --cc) {
      int ns = suffix + (int)cg[cc];
      if (ns >= KPRE) { c = cc; break; }
      suffix = ns;
    }
    s_c = c; s_sfx = suffix;
  }
  __syncthreads();
  int cstar = s_c;
  if (t < 128) {
    const u16* hb = histr + (size_t)b * HB * NBUCKET;
    int bsum = 0;
    for (int r = 0; r < HB; ++r) bsum += hb[(size_t)r * NBUCKET + cstar * 128 + t];
    bt[t] = bsum;
  }
  __syncthreads();
  if (t == 0) {
    int run = s_sfx, T = 0;
    for (int k = 127; k >= 0; --k) {
      run += bt[k];
      if (run >= KPRE) { T = cstar * 128 + k; break; }
    }
    meta[b] = T;
  }
}

// ---- 3: compact candidates (bucket >= T); ballot -> LDS -> 1 global atomic/block ----
__global__ __launch_bounds__(256) void k_compact(const float* __restrict__ probs, const int* __restrict__ meta,
                                                 int* __restrict__ cnt, u64* __restrict__ cand) {
  __shared__ int wbase[4];
  __shared__ int btot, bbase;
  int b = blockIdx.y;
  int T = meta[b];
  const int n4 = NANCH / 2;
  int i = blockIdx.x * 256 + threadIdx.x;
  int lane = threadIdx.x & 63, wv = threadIdx.x >> 6;
  if (threadIdx.x == 0) btot = 0;
  __syncthreads();
  u32 bits0 = 0, bits1 = 0;
  bool p0 = false, p1 = false;
  if (i < n4) {
    float4 v = ((const float4*)(probs + (size_t)b * NANCH * 2))[i];
    bits0 = __float_as_uint(v.y); bits1 = __float_as_uint(v.w);
    p0 = (int)(bits0 >> 15) >= T; p1 = (int)(bits1 >> 15) >= T;
  }
  u64 m0 = __ballot(p0);
  u64 m1 = __ballot(p1);
  int c0 = (int)__popcll(m0), c1 = (int)__popcll(m1);
  if (lane == 0) wbase[wv] = (c0 + c1) ? atomicAdd(&btot, c0 + c1) : 0;
  __syncthreads();
  if (threadIdx.x == 0 && btot) bbase = atomicAdd(&cnt[b * 32], btot);
  __syncthreads();
  if (p0 | p1) {
    int base = bbase + wbase[wv];
    if (p0) {
      int pos = base + (int)__popcll(m0 & ((1ull << lane) - 1ull));
      if (pos < CAP) cand[(size_t)b * CAP + pos] = ((u64)bits0 << 32) | (u32)(~(u32)(2 * i));
    }
    if (p1) {
      int pos = base + c0 + (int)__popcll(m1 & ((1ull << lane) - 1ull));
      if (pos < CAP) cand[(size_t)b * CAP + pos] = ((u64)bits1 << 32) | (u32)(~(u32)(2 * i + 1));
    }
  }
}

// ---- 4a: local bitonic sort of 1024-element runs (desc), 8 runs per batch ----
__global__ __launch_bounds__(1024) void k_lsort(u64* __restrict__ cand, const int* __restrict__ cnt) {
  __shared__ u64 sk[1024];  // 8 KiB
  int b = blockIdx.y, run = blockIdx.x;
  int C = cnt[b * 32];
  int g = run * 1024 + threadIdx.x;
  sk[threadIdx.x] = (g < C) ? cand[(size_t)b * CAP + g] : 0ull;
  __syncthreads();
  for (int ksz = 2; ksz <= 1024; ksz <<= 1) {
    for (int j = ksz >> 1; j > 0; j >>= 1) {
      int i = threadIdx.x;
      int ixj = i ^ j;
      if (ixj > i) {
        u64 a = sk[i], c2 = sk[ixj];
        bool up = (i & ksz) == 0;
        if ((a < c2) == up) { sk[i] = c2; sk[ixj] = a; }  // descending
      }
      __syncthreads();
    }
  }
  cand[(size_t)b * CAP + g] = sk[threadIdx.x];
}

// merge-path partition for DESCENDING keys, stable toward X (uses >=)
__device__ inline int mp_search(const u64* X, int n1, const u64* Y, int n2, int d) {
  int lo = d - n2; if (lo < 0) lo = 0;
  int hi = d < n1 ? d : n1;
  while (lo < hi) {
    int m = (lo + hi) >> 1;
    if (X[m] >= Y[d - 1 - m]) lo = m + 1; else hi = m;
  }
  return lo;
}

// ---- 4b: merge 8 sorted 1024-runs -> top-6000, fused gather + box decode ----
__global__ __launch_bounds__(1024) void k_merge(const u64* __restrict__ cand,
                                                const float* __restrict__ anchors, const float* __restrict__ bbox,
                                                float4* __restrict__ boxes) {
  __shared__ u64 A[CAP];   // 64 KiB
  __shared__ u64 Bf[CAP];  // 64 KiB
  int b = blockIdx.x;
  int t = threadIdx.x;
  for (int r = t; r < CAP; r += 1024) A[r] = cand[(size_t)b * CAP + r];
  __syncthreads();
  {
    int m = t >> 8, tt = t & 255;
    const u64* X = A + m * 2048; const u64* Y = X + 1024;
    u64* O = Bf + m * 2048;
    int d = tt * 8;
    int i = mp_search(X, 1024, Y, 1024, d), j = d - i;
    #pragma unroll
    for (int k = 0; k < 8; ++k) {
      bool tx = (i < 1024) && (j >= 1024 || X[i] >= Y[j]);
      O[d + k] = tx ? X[i++] : Y[j++];
    }
  }
  __syncthreads();
  {
    int m = t >> 9, tt = t & 511;
    const u64* X = Bf + m * 4096; const u64* Y = X + 2048;
    u64* O = A + m * 4096;
    int d = tt * 8;
    int i = mp_search(X, 2048, Y, 2048, d), j = d - i;
    #pragma unroll
    for (int k = 0; k < 8; ++k) {
      bool tx = (i < 2048) && (j >= 2048 || X[i] >= Y[j]);
      O[d + k] = tx ? X[i++] : Y[j++];
    }
  }
  __syncthreads();
  {
    const u64* X = A; const u64* Y = A + 4096;
    int d = t * 8;
    if (d < KPRE) {
      int i = mp_search(X, 4096, Y, 4096, d), j = d - i;
      int lim = KPRE - d; if (lim > 8) lim = 8;
      for (int k = 0; k < lim; ++k) {
        bool tx = (i < 4096) && (j >= 4096 || X[i] >= Y[j]);
        u64 key = tx ? X[i++] : Y[j++];
        u32 idx = ~(u32)key;
        const float4 a  = ((const float4*)anchors)[(size_t)b * NANCH + idx];
        const float4 dr = ((const float4*)bbox)[(size_t)b * NANCH + idx];
        float d0 = __fmul_rn(dr.x, 0.1f), d1 = __fmul_rn(dr.y, 0.1f);
        float d2 = __fmul_rn(dr.z, 0.2f), d3 = __fmul_rn(dr.w, 0.2f);
        float h = __fsub_rn(a.z, a.x);
        float w = __fsub_rn(a.w, a.y);
        float cy = __fadd_rn(a.x, __fmul_rn(0.5f, h));
        float cx = __fadd_rn(a.y, __fmul_rn(0.5f, w));
        cy = __fadd_rn(cy, __fmul_rn(d0, h));
        cx = __fadd_rn(cx, __fmul_rn(d1, w));
        h = __fmul_rn(h, (float)exp((double)d2));
        w = __fmul_rn(w, (float)exp((double)d3));
        float y1 = __fsub_rn(cy, __fmul_rn(0.5f, h));
        float x1 = __fsub_rn(cx, __fmul_rn(0.5f, w));
        float4 o; o.x = y1; o.y = x1; o.z = __fadd_rn(y1, h); o.w = __fadd_rn(x1, w);
        boxes[(size_t)b * KPRE + d + k] = o;
      }
    }
  }
}

// ---- 5: suppression bitmask M[b][r][w], bit k = (IoU(r, c=w*64+k) > thr) && (c > r) ----
// Exact criterion: RN(inter/uni) > 0.7f <=> (double)inter >= MD*(double)uni, MD = (double)0.7f + 2^-25.
// Hot loop uses a pure-f32 band test: inter >= RN(uni*0.700001f) => certainly true (margin 9e-7 >> 1ulp);
// inter < RN(uni*0.699999f) => certainly false. The ~2e-6-wide ambiguous band (~1e-5 probability) is
// re-evaluated exactly in f64 in a rare fallback loop. Bit-exact overall.
// Each thread owns TWO rows (r, r+128) x 4 words: LDS column reads amortized over 2 IoUs.
__global__ __launch_bounds__(256) void k_mask(const float4* __restrict__ boxes, u64* __restrict__ M) {
  const double MD = (double)0.7f + 0x1.0p-25;
  const float CHI = 0.700001f, CLO = 0.699999f;
  __shared__ float4 sb[WB * 64];
  __shared__ float  sa[WB * 64];
  int b = blockIdx.y;
  int tile = NTILE - 1 - blockIdx.x;  // heavy tiles dispatched first
  int ch = 0, base = 0;
  #pragma unroll
  for (int j = 0; j < NCH; ++j) {
    int n = (j < 11) ? 2 * (j + 1) : 24;
    if (tile >= base + n) { base += n; ch = j + 1; }
  }
  int rb = tile - base;

  int w0 = ch * WB;
  int c0 = w0 << 6;
  const float4* bb = boxes + (size_t)b * KPRE;

  for (int t = threadIdx.x; t < WB * 64; t += 256) {
    int c = c0 + t;
    float4 v; v.x = 0.f; v.y = 0.f; v.z = 0.f; v.w = 0.f;
    if (c < KPRE) v = bb[c];
    sb[t] = v;
    sa[t] = __fmul_rn(__fsub_rn(v.z, v.x), __fsub_rn(v.w, v.y));
  }
  __syncthreads();

  int half = threadIdx.x & 1;
  int r0 = rb * 256 + (threadIdx.x >> 1);
  int r1 = r0 + 128;
  bool v0 = r0 < KPRE, v1 = r1 < KPRE;
  float4 z4; z4.x = 0.f; z4.y = 0.f; z4.z = 0.f; z4.w = 0.f;
  float4 br0 = v0 ? bb[r0] : z4;
  float4 br1 = v1 ? bb[r1] : z4;
  float ar0 = __fmul_rn(__fsub_rn(br0.z, br0.x), __fsub_rn(br0.w, br0.y));
  float ar1 = __fmul_rn(__fsub_rn(br1.z, br1.x), __fsub_rn(br1.w, br1.y));
  int wbase = w0 + 4 * half;

  u64 buf0[4], buf1[4];
  #pragma unroll
  for (int k = 0; k < 4; ++k) {
    int w = wbase + k;
    int cbase = w << 6;
    int tb = (w - w0) << 6;
    bool n0 = v0 && (w < MW) && (cbase + 63 > r0);
    bool n1 = v1 && (w < MW) && (cbase + 63 > r1);
    u64 bits0 = 0ull, bits1 = 0ull;
    if (n0 | n1) {
      u64 amb0 = 0ull, amb1 = 0ull;
      #pragma unroll 16
      for (int k2 = 0; k2 < 64; ++k2) {
        float4 bc = sb[tb + k2];
        float ac = sa[tb + k2];
        {
          float iy1 = fmaxf(br0.x, bc.x), ix1 = fmaxf(br0.y, bc.y);
          float iy2 = fminf(br0.z, bc.z), ix2 = fminf(br0.w, bc.w);
          float ih = fmaxf(__fsub_rn(iy2, iy1), 0.f), iw = fmaxf(__fsub_rn(ix2, ix1), 0.f);
          float inter = __fmul_rn(ih, iw);
          float uni = __fsub_rn(__fadd_rn(ar0, ac), inter);
          bool hi = inter >= __fmul_rn(uni, CHI);
          bool lo = inter >= __fmul_rn(uni, CLO);
          if (hi) bits0 |= (1ull << k2);
          if (lo != hi) amb0 |= (1ull << k2);
        }
        {
          float iy1 = fmaxf(br1.x, bc.x), ix1 = fmaxf(br1.y, bc.y);
          float iy2 = fminf(br1.z, bc.z), ix2 = fminf(br1.w, bc.w);
          float ih = fmaxf(__fsub_rn(iy2, iy1), 0.f), iw = fmaxf(__fsub_rn(ix2, ix1), 0.f);
          float inter = __fmul_rn(ih, iw);
          float uni = __fsub_rn(__fadd_rn(ar1, ac), inter);
          bool hi = inter >= __fmul_rn(uni, CHI);
          bool lo = inter >= __fmul_rn(uni, CLO);
          if (hi) bits1 |= (1ull << k2);
          if (lo != hi) amb1 |= (1ull << k2);
        }
      }
      // exact f64 fallback for ambiguous-band columns (rare)
      while (amb0) {
        int k2 = (int)__builtin_ctzll(amb0); amb0 &= amb0 - 1;
        float4 bc = sb[tb + k2]; float ac = sa[tb + k2];
        float iy1 = fmaxf(br0.x, bc.x), ix1 = fmaxf(br0.y, bc.y);
        float iy2 = fminf(br0.z, bc.z), ix2 = fminf(br0.w, bc.w);
        float ih = fmaxf(__fsub_rn(iy2, iy1), 0.f), iw = fmaxf(__fsub_rn(ix2, ix1), 0.f);
        float inter = __fmul_rn(ih, iw);
        float uni = __fsub_rn(__fadd_rn(ar0, ac), inter);
        if ((double)inter >= MD * (double)uni) bits0 |= (1ull << k2);
      }
      while (amb1) {
        int k2 = (int)__builtin_ctzll(amb1); amb1 &= amb1 - 1;
        float4 bc = sb[tb + k2]; float ac = sa[tb + k2];
        float iy1 = fmaxf(br1.x, bc.x), ix1 = fmaxf(br1.y, bc.y);
        float iy2 = fminf(br1.z, bc.z), ix2 = fminf(br1.w, bc.w);
        float ih = fmaxf(__fsub_rn(iy2, iy1), 0.f), iw = fmaxf(__fsub_rn(ix2, ix1), 0.f);
        float inter = __fmul_rn(ih, iw);
        float uni = __fsub_rn(__fadd_rn(ar1, ac), inter);
        if ((double)inter >= MD * (double)uni) bits1 |= (1ull << k2);
      }
      if (n0 && cbase <= r0) bits0 &= ~((r0 - cbase >= 63) ? ~0ull : ((1ull << (r0 - cbase + 1)) - 1ull));
      if (n1 && cbase <= r1) bits1 &= ~((r1 - cbase >= 63) ? ~0ull : ((1ull << (r1 - cbase + 1)) - 1ull));
    }
    buf0[k] = n0 ? bits0 : 0ull;
    buf1[k] = n1 ? bits1 : 0ull;
  }
  if (v0) {
    ulonglong2* dst = (ulonglong2*)(M + ((size_t)b * KPRE + r0) * MSTRIDE + wbase);
    ulonglong2 p; p.x = buf0[0]; p.y = buf0[1]; dst[0] = p;
    p.x = buf0[2]; p.y = buf0[3]; dst[1] = p;
  }
  if (v1) {
    ulonglong2* dst = (ulonglong2*)(M + ((size_t)b * KPRE + r1) * MSTRIDE + wbase);
    ulonglong2 p; p.x = buf1[0]; p.y = buf1[1]; dst[0] = p;
    p.x = buf1[2]; p.y = buf1[3]; dst[1] = p;
  }
}

// ---- 6: block-parallel greedy NMS scan — one block (4 waves) per batch ----
__global__ __launch_bounds__(256) void k_scan(const u64* __restrict__ M, const float4* __restrict__ boxes,
                                              float4* __restrict__ out) {
  __shared__ u64 xch[2][4];
  __shared__ u64 fin[MW];
  __shared__ int pfx[MW];
  int b = blockIdx.x;
  int tid = threadIdx.x;
  int lane = tid & 63;
  int wv = tid >> 6;
  const u64* Mb = M + (size_t)b * KPRE * MSTRIDE;

  if (tid < MW) fin[tid] = 0ull;

  u64 kw0 = ~0ull, kw1 = ~0ull;
  u64 cur = ~0ull;
  u64 dw = Mb[(size_t)lane * MSTRIDE + 0];
  int count = 0;

  for (int w = 0; w < MW; ++w) {
    int rem = KPRE - (w << 6);
    u64 valid = (rem >= 64) ? ~0ull : ((1ull << rem) - 1ull);
    cur &= valid;

    u64 nz = __ballot(dw != 0ull);
    u64 pend = cur & nz;
    while (pend) {
      int k = (int)__builtin_ctzll(pend);
      u64 d = shfl64(dw, k);
      cur &= ~d;
      pend &= (pend - 1);
      pend &= cur;
    }

    if (tid == 0) fin[w] = cur;
    count += (int)__popcll(cur);
    if (count >= PROP || w == MW - 1) break;

    {
      int r = ((w + 1) << 6) + lane;
      dw = (r < KPRE) ? Mb[(size_t)r * MSTRIDE + (w + 1)] : 0ull;
    }

    bool lactive = (lane < 47) && (2 * lane + 1 >= w + 1);
    ulonglong2 mm[16];
    #pragma unroll
    for (int kk = 0; kk < 16; ++kk) {
      int r = (w << 6) + wv + (kk << 2);
      ulonglong2 t2; t2.x = 0ull; t2.y = 0ull;
      if (lactive && r < KPRE)
        t2 = ((const ulonglong2*)(Mb + (size_t)r * MSTRIDE))[lane];
      mm[kk] = t2;
    }
    #pragma unroll
    for (int kk = 0; kk < 16; ++kk) {
      int k = wv + (kk << 2);
      u64 sel = 0ull - ((cur >> k) & 1ull);
      kw0 &= ~(mm[kk].x & sel);
      kw1 &= ~(mm[kk].y & sel);
    }

    int nw = w + 1;
    if (lane == (nw >> 1)) xch[nw & 1][wv] = (nw & 1) ? kw1 : kw0;
    __syncthreads();
    cur = xch[nw & 1][0] & xch[nw & 1][1] & xch[nw & 1][2] & xch[nw & 1][3];
  }
  __syncthreads();

  if (tid == 0) {
    int s = 0;
    for (int t = 0; t < MW; ++t) { pfx[t] = s; s += (int)__popcll(fin[t]); }
  }
  __syncthreads();

  const float4* bb = boxes + (size_t)b * KPRE;
  float4* ob = out + (size_t)b * PROP;
  if (tid < MW) {
    u64 bits = fin[tid];
    int slot = pfx[tid];
    while (bits && slot < PROP) {
      int k = (int)__builtin_ctzll(bits);
      ob[slot] = bb[(tid << 6) + k];
      ++slot;
      bits &= bits - 1;
    }
  }
}

extern "C" void kernel_launch(void* const* d_in, const int* in_sizes, int n_in,
                              void* d_out, int out_size, void* d_ws, size_t ws_size,
                              hipStream_t stream) {
  const float* probs   = (const float*)d_in[0];
  const float* bbox    = (const float*)d_in[1];
  const float* anchors = (const float*)d_in[2];
  char* ws = (char*)d_ws;
  int* meta    = (int*)(ws + OFF_META);          // T[8]
  int* cnt     = (int*)(ws + OFF_META + 4096);   // cnt[b*32], 128B-padded
  u32* coarse  = (u32*)(ws + OFF_META + 8192);   // u32[8][256]
  u64* cand    = (u64*)(ws + OFF_CAND);
  float4* boxes = (float4*)(ws + OFF_BOXES);
  u64* M       = (u64*)(ws + OFF_M);
  u16* histr   = (u16*)(ws + OFF_M);             // reuse M region (dead until k_mask)
  float4* out  = (float4*)d_out;

  (void)hipMemsetAsync(ws + OFF_META + 4096, 0, 12288, stream);  // cnt + coarse
  (void)hipMemsetAsync(d_out, 0, (size_t)out_size * 4, stream);

  dim3 gh(HB, BATCH);
  k_hist<<<gh, 1024, 0, stream>>>(probs, histr, coarse);
  k_thresh<<<BATCH, 256, 0, stream>>>(histr, coarse, meta);
  dim3 gc((NANCH / 2 + 255) / 256, BATCH);
  k_compact<<<gc, 256, 0, stream>>>(probs, meta, cnt, cand);
  dim3 gl(8, BATCH);
  k_lsort<<<gl, 1024, 0, stream>>>(cand, cnt);
  k_merge<<<BATCH, 1024, 0, stream>>>(cand, anchors, bbox, boxes);
  dim3 gm(NTILE, BATCH);
  k_mask<<<gm, 256, 0, stream>>>(boxes, M);
  k_scan<<<BATCH, 256, 0, stream>>>(M, boxes, out);
}